// Round 7
// baseline (238.893 us; speedup 1.0000x reference)
//
#include <hip/hip_runtime.h>
#include <hip/hip_bf16.h>
#include <math.h>

#define N_NODES 100000
#define N_EDGES 600000
#define H 128
#define LH 256
#define CDIM 8
#define NB_STATS 256
#define NT128 ((N_NODES + 127) / 128)   // 782 (128-row tiles, fused kernel)
#define ELLW 64                          // fixed ELL width; P(deg>=64)~1e-40 for Poisson(6)
#define NB_NODE ((N_NODES + 255) / 256)  // 391 blocks carry node/normalize work

// --- two-level atomic-free binning (proven R4: -20us vs global atomics) ---
#define NBUCK 391                        // dst >> 8 ; 100000>>8 = 390 max
#define NBLK_P1 64
#define EPB (N_EDGES / NBLK_P1)          // 9375 edges per P1 block
#define CAP 72                           // per-(block,bucket) capacity; mean 24,
                                         // P(Poisson(24)>=72)~3e-14 x 25K cells

typedef __attribute__((ext_vector_type(8))) short short8;
typedef __attribute__((ext_vector_type(4))) float floatx4;

// ------------- workspace layout (4-byte words) -------------
#define OFF_PART   0                                  // 256*11 = 2816
#define OFF_DEG    2816                               // N_NODES
#define OFF_H0     (OFF_DEG + N_NODES)                // 102816, 16B aligned
#define OFF_ELL    (OFF_H0 + N_NODES*4)               // 502816, N_NODES*64 words
#define OFF_CNTT   (OFF_ELL + N_NODES*ELLW)           // 6902816, 391*64 words
#define OFF_SCR    (OFF_CNTT + NBUCK*NBLK_P1)         // 6927840, int2-aligned
#define OFF_WPK2   (OFF_SCR + NBUCK*NBLK_P1*CAP*2)    // 10531296, 16B aligned
#define OFF_WPK1   (OFF_WPK2 + 16384)
#define OFF_W2PK   (OFF_WPK1 + 16384)
#define OFF_XB     (OFF_W2PK + 2048)                  // 10566112, 16B aligned
// end = 10566112 + 12.8M words = 23.37M words ~= 93.5 MB (< 103 MB proven)

__device__ __forceinline__ float rot_c() { return cosf(1.57079632679489661923f); }
__device__ __forceinline__ float rot_s() { return sinf(1.57079632679489661923f); }
__device__ __forceinline__ float bfhi(unsigned v) { return __uint_as_float(v & 0xffff0000u); }
__device__ __forceinline__ float bflo(unsigned v) { return __uint_as_float(v << 16); }
__device__ __forceinline__ unsigned short bfu(float f) {
    __hip_bfloat16 h = __float2bfloat16(f);
    return *(unsigned short*)&h;
}
// fast tanh: 1 - 2/(e^{2x}+1). Exact at +-inf (rcp(inf)=0), rel err ~1e-6.
__device__ __forceinline__ float ftanh(float x) {
    float e = __expf(2.0f * x);
    return 1.0f - 2.0f * __builtin_amdgcn_rcpf(e + 1.0f);
}

// ---------------- kernel A: stats partials (blocks 0..255) + P1 edge
// partition (blocks 256..319). No dependency between the two roles.
__global__ __launch_bounds__(256) void statsPart_k(const float* __restrict__ x,
        float* __restrict__ part, const int* __restrict__ ei,
        int* __restrict__ cntT, int2* __restrict__ scratch) {
    __shared__ float red[4][11];
    __shared__ int lcnt[NBUCK];
    int tid = threadIdx.x;

    if (blockIdx.x >= NB_STATS) {
        // ---- P1 role: partition 9375 edges into 391 buckets, LDS atomics only
        int blk = blockIdx.x - NB_STATS;
        for (int i = tid; i < NBUCK; i += 256) lcnt[i] = 0;
        __syncthreads();
        int base = blk * EPB;
        for (int e = base + tid; e < base + EPB; e += 256) {
            int s = ei[e], d = ei[N_EDGES + e];
            int b = d >> 8;
            int pos = atomicAdd(&lcnt[b], 1);          // LDS atomic
            scratch[(b * NBLK_P1 + blk) * CAP + pos] = make_int2(s, d);
        }
        __syncthreads();
        for (int i = tid; i < NBUCK; i += 256)
            cntT[i * NBLK_P1 + blk] = lcnt[i];
        return;
    }

    // ---- stats role (fixed stride: only NB_STATS blocks participate)
    const float c = rot_c(), sn = rot_s();
    float mn0 = INFINITY, mx0 = -INFINITY, mn1 = INFINITY, mx1 = -INFINITY;
    float s0 = 0.f, s1 = 0.f, sr0 = 0.f, sr1 = 0.f;
    float mxr0 = -INFINITY, mxr1 = -INFINITY, mxa = -INFINITY;
    for (int i = blockIdx.x * 256 + tid; i < N_NODES; i += NB_STATS * 256) {
        float x0 = x[3*i], x1 = x[3*i+1], a = x[3*i+2];
        float r0 = c*x0 - sn*x1;
        float r1 = sn*x0 + c*x1;
        mn0 = fminf(mn0, x0); mx0 = fmaxf(mx0, x0);
        mn1 = fminf(mn1, x1); mx1 = fmaxf(mx1, x1);
        s0 += x0; s1 += x1; sr0 += r0; sr1 += r1;
        mxr0 = fmaxf(mxr0, r0); mxr1 = fmaxf(mxr1, r1);
        mxa = fmaxf(mxa, a);
    }
    float vals[11] = {mn0, mx0, mn1, mx1, s0, s1, sr0, sr1, mxr0, mxr1, mxa};
    int lane = tid & 63, wave = tid >> 6;
    #pragma unroll
    for (int v = 0; v < 11; v++) {
        const int op = (v==0||v==2) ? 0 : (v>=4 && v<=7) ? 2 : 1;
        float val = vals[v];
        #pragma unroll
        for (int off = 32; off > 0; off >>= 1) {
            float o = __shfl_down(val, off);
            val = (op==0) ? fminf(val,o) : (op==1) ? fmaxf(val,o) : (val+o);
        }
        if (lane == 0) red[wave][v] = val;
    }
    __syncthreads();
    if (tid < 11) {
        int v = tid;
        int op = (v==0||v==2) ? 0 : (v>=4 && v<=7) ? 2 : 1;
        float a = red[0][v], b = red[1][v], cc = red[2][v], d = red[3][v];
        float r = (op==0) ? fminf(fminf(a,b), fminf(cc,d))
                : (op==1) ? fmaxf(fmaxf(a,b), fmaxf(cc,d))
                : (a + b + cc + d);
        part[blockIdx.x * 11 + v] = r;
    }
}

// ---------------- kernel B: P2 bucket->ELL binning (blocks 0..390) +
// normalize/pack (blocks 391..781). Both depend only on kernel A.
__global__ __launch_bounds__(256) void binNorm_k(const float* __restrict__ x,
        const float* __restrict__ part, float4* __restrict__ h0,
        const float* __restrict__ Wl2, const float* __restrict__ Wr2,
        const float* __restrict__ W1, const float* __restrict__ W2,
        __hip_bfloat16* __restrict__ Wpk2, __hip_bfloat16* __restrict__ Wpk1,
        __hip_bfloat16* __restrict__ W2pk,
        const int* __restrict__ cntT, const int2* __restrict__ scratch,
        int* __restrict__ ell, int* __restrict__ deg) {
    __shared__ int pref[NBLK_P1 + 1];
    __shared__ int ncnt[256];
    __shared__ float res[11];
    int tid = threadIdx.x;

    if (blockIdx.x < NBUCK) {
        // ---- P2 role: bin bucket b (256 nodes) into final ELL, LDS atomics only
        int b = blockIdx.x;
        ncnt[tid] = 0;
        if (tid < NBLK_P1) pref[tid + 1] = cntT[b * NBLK_P1 + tid];
        __syncthreads();
        if (tid == 0) {
            pref[0] = 0;
            int acc = 0;
            #pragma unroll 8
            for (int j = 0; j < NBLK_P1; j++) { acc += pref[j+1]; pref[j+1] = acc; }
        }
        __syncthreads();
        int T = pref[NBLK_P1];
        for (int f = tid; f < T; f += 256) {
            int lo = 0, hi = NBLK_P1;           // find j: pref[j] <= f < pref[j+1]
            while (hi - lo > 1) {
                int mid = (lo + hi) >> 1;
                if (pref[mid] <= f) lo = mid; else hi = mid;
            }
            int2 sd = scratch[(b * NBLK_P1 + lo) * CAP + (f - pref[lo])];
            int pos = atomicAdd(&ncnt[sd.y & 255], 1);   // LDS atomic
            ell[(sd.y << 6) + pos] = sd.x;
        }
        __syncthreads();
        int n = (b << 8) + tid;
        if (n < N_NODES) deg[n] = ncnt[tid];
        return;
    }

    // ---- normalize role
    int nb = blockIdx.x - NBUCK;
    int i = nb * 256 + tid;
    if (tid < 64) {
        const int ops[11] = {0,1,0,1,2,2,2,2,1,1,1};
        for (int v = 0; v < 11; v++) {
            float val = part[tid * 11 + v];
            #pragma unroll
            for (int p = 1; p < 4; p++) {
                float o = part[(tid + p*64) * 11 + v];
                val = (ops[v]==0) ? fminf(val,o) : (ops[v]==1) ? fmaxf(val,o) : (val+o);
            }
            #pragma unroll
            for (int off = 32; off > 0; off >>= 1) {
                float o = __shfl_down(val, off);
                val = (ops[v]==0) ? fminf(val,o) : (ops[v]==1) ? fmaxf(val,o) : (val+o);
            }
            if (tid == 0) res[v] = val;
        }
    }
    __syncthreads();
    int rotate = (res[3] - res[2]) > (res[1] - res[0]);
    float mean0 = (rotate ? res[6] : res[4]) / (float)N_NODES;
    float mean1 = (rotate ? res[7] : res[5]) / (float)N_NODES;
    float imx0  = 1.0f / (rotate ? res[8] : res[1]);
    float imx1  = 1.0f / (rotate ? res[9] : res[3]);
    float imxa  = 1.0f / res[10];

    if (i < N_NODES) {
        const float c = rot_c(), sn = rot_s();
        float x0 = x[3*i], x1 = x[3*i+1], a = x[3*i+2];
        float u0 = rotate ? (c*x0 - sn*x1) : x0;
        float u1 = rotate ? (sn*x0 + c*x1) : x1;
        h0[i] = make_float4((u0 - mean0) * imx0, (u1 - mean1) * imx1, a * imxa, 0.f);
    }
    int idx = i;
    if (idx < 32768) {                       // Wpk2[ks8][nt8][lane64][j8], K=256,N=128
        int j = idx & 7, lane = (idx >> 3) & 63, nt = (idx >> 9) & 7, ks = idx >> 12;
        int k = ks*32 + (lane >> 4)*8 + j;
        int n = nt*16 + (lane & 15);
        float v = (k < 128) ? Wl2[n*H + k] : Wr2[n*H + (k - 128)];
        Wpk2[idx] = __float2bfloat16(v);
    } else if (idx < 65536) {                // Wpk1[ks4][nt16][lane64][j8], K=128,N=256
        int i2 = idx - 32768;
        int j = i2 & 7, lane = (i2 >> 3) & 63, nt = (i2 >> 9) & 15, ks = i2 >> 13;
        int k = ks*32 + (lane >> 4)*8 + j;
        int n = nt*16 + (lane & 15);
        Wpk1[i2] = __float2bfloat16(W1[n*H + k]);
    } else if (idx < 69632) {                // W2pk[ks8][lane64][j8], K=256,N=16(8 real)
        int i3 = idx - 65536;
        int j = i3 & 7, lane = (i3 >> 3) & 63, ks = i3 >> 9;
        int k = ks*32 + (lane >> 4)*8 + j;
        int n = lane & 15;
        W2pk[i3] = __float2bfloat16((n < CDIM) ? W2[n*LH + k] : 0.f);
    }
}

// ---------------- fused agg1 + conv1 dense ----------------
__global__ __launch_bounds__(256) void agg1conv1_k(const float4* __restrict__ h0,
        const int* __restrict__ deg, const int* __restrict__ ell,
        const float* __restrict__ Wl1, const float* __restrict__ bl1,
        const float* __restrict__ Wr1, __hip_bfloat16* __restrict__ Xb) {
    __shared__ float wl[H*3], wr[H*3], bb[H];
    __shared__ float4 sa[256];
    int tid = threadIdx.x;
    for (int i = tid; i < H*3; i += 256) { wl[i] = Wl1[i]; wr[i] = Wr1[i]; }
    if (tid < H) bb[tid] = bl1[tid];
    int base = blockIdx.x * 256;
    int n = base + tid;
    float4 av = make_float4(0.f, 0.f, 0.f, 0.f);
    if (n < N_NODES) {
        int dg = deg[n];
        int start = n << 6, end = start + dg;
        float a0 = 0.f, a1 = 0.f, a2 = 0.f;
        int e = start;
        for (; e + 3 < end; e += 4) {
            int s0 = ell[e], s1 = ell[e+1], s2 = ell[e+2], s3 = ell[e+3];
            float4 v0 = h0[s0];
            float4 v1 = h0[s1];
            float4 v2 = h0[s2];
            float4 v3 = h0[s3];
            a0 += (v0.x + v1.x) + (v2.x + v3.x);
            a1 += (v0.y + v1.y) + (v2.y + v3.y);
            a2 += (v0.z + v1.z) + (v2.z + v3.z);
        }
        for (; e < end; e++) {
            float4 v = h0[ell[e]];
            a0 += v.x; a1 += v.y; a2 += v.z;
        }
        float inv = 1.0f / (float)max(dg, 1);
        av = make_float4(a0 * inv, a1 * inv, a2 * inv, 0.f);
    }
    sa[tid] = av;
    __syncthreads();
    int sub = tid >> 6;
    int j2 = (tid & 63) * 2;
    for (int i = 0; i < 64; i++) {
        int loc = i * 4 + sub;
        int nn = base + loc;
        if (nn >= N_NODES) break;
        float4 a = sa[loc];
        float4 xv = h0[nn];
        float o0 = wl[3*j2+0]*a.x + wl[3*j2+1]*a.y + wl[3*j2+2]*a.z + bb[j2]
                 + wr[3*j2+0]*xv.x + wr[3*j2+1]*xv.y + wr[3*j2+2]*xv.z;
        float o1 = wl[3*j2+3]*a.x + wl[3*j2+4]*a.y + wl[3*j2+5]*a.z + bb[j2+1]
                 + wr[3*j2+3]*xv.x + wr[3*j2+4]*xv.y + wr[3*j2+5]*xv.z;
        unsigned pv = ((unsigned)bfu(ftanh(o1)) << 16) | (unsigned)bfu(ftanh(o0));
        *(unsigned*)&Xb[(size_t)nn*256 + 128 + j2] = pv;
    }
}

// ---------------- agg2: mean of h1 (bf16) -> Xb[n][0..127]
__global__ void agg2_k(__hip_bfloat16* __restrict__ Xb, const int* __restrict__ deg,
                       const int* __restrict__ ell) {
    int lane = threadIdx.x & 15;
    int n = blockIdx.x * 16 + (threadIdx.x >> 4);
    int dg = deg[n];
    int start = n << 6, end = start + dg;
    const short* XbS = (const short*)Xb;
    float a0=0.f,a1=0.f,a2=0.f,a3=0.f,a4=0.f,a5=0.f,a6=0.f,a7=0.f;
    int e = start;
    for (; e + 1 < end; e += 2) {
        int s0 = ell[e], s1 = ell[e+1];
        uint4 v0 = *(const uint4*)&XbS[(size_t)s0*256 + 128 + lane*8];
        uint4 v1 = *(const uint4*)&XbS[(size_t)s1*256 + 128 + lane*8];
        a0 += bflo(v0.x) + bflo(v1.x); a1 += bfhi(v0.x) + bfhi(v1.x);
        a2 += bflo(v0.y) + bflo(v1.y); a3 += bfhi(v0.y) + bfhi(v1.y);
        a4 += bflo(v0.z) + bflo(v1.z); a5 += bfhi(v0.z) + bfhi(v1.z);
        a6 += bflo(v0.w) + bflo(v1.w); a7 += bfhi(v0.w) + bfhi(v1.w);
    }
    if (e < end) {
        int s0 = ell[e];
        uint4 v0 = *(const uint4*)&XbS[(size_t)s0*256 + 128 + lane*8];
        a0 += bflo(v0.x); a1 += bfhi(v0.x);
        a2 += bflo(v0.y); a3 += bfhi(v0.y);
        a4 += bflo(v0.z); a5 += bfhi(v0.z);
        a6 += bflo(v0.w); a7 += bfhi(v0.w);
    }
    float inv = 1.0f / (float)max(dg, 1);
    uint4 o;
    o.x = ((unsigned)bfu(a1*inv) << 16) | (unsigned)bfu(a0*inv);
    o.y = ((unsigned)bfu(a3*inv) << 16) | (unsigned)bfu(a2*inv);
    o.z = ((unsigned)bfu(a5*inv) << 16) | (unsigned)bfu(a4*inv);
    o.w = ((unsigned)bfu(a7*inv) << 16) | (unsigned)bfu(a6*inv);
    *(uint4*)&Xb[(size_t)n*256 + lane*8] = o;
}

// ---------------- FUSED conv2 + MLP + softmax (v7) ----------------
// R6 post-mortem: launch_bounds(512,4) capped UNIFIED regs at 128/wave ->
// VGPR_Count 64, no load pipelining, latency-bound (MfmaUtil 10.7%).
// v7: 256-thread blocks, each WAVE owns 32 rows (two 16-row groups) ->
// every B-fragment feeds 2 MFMAs (B-traffic halved, ILP doubled).
// GEMM1 split into two 8-col passes (acc1 = 8x2 = 64 AGPR) with h2
// persisted in a per-wave swizzled LDS slice. launch_bounds(256,2) ->
// 256 unified regs (est ~220, no spill), LDS 37KB, 2 blocks/CU, 0 barriers.
__global__ __launch_bounds__(256, 2) void conv2mlp_k(const __hip_bfloat16* __restrict__ Xb,
        const __hip_bfloat16* __restrict__ Wpk2, const float* __restrict__ bl2,
        const __hip_bfloat16* __restrict__ Wpk1, const float* __restrict__ b1,
        const __hip_bfloat16* __restrict__ W2pk, const float* __restrict__ b2,
        float* __restrict__ out) {
    __shared__ short Hs[4 * 2 * 2048];   // 32KB: per-wave 2x(16x128) swizzled h2
    __shared__ short Ms[4 * 640];        // 5KB: per-wave 16x40 t mini-slice
    int tid = threadIdx.x;
    int lane = tid & 63, wave = tid >> 6;
    int quad = lane >> 4, m = lane & 15, c0 = lane & 15;
    short* Hw = &Hs[wave * 4096];
    short* Tw = &Ms[wave * 640];
    const short* Bg2 = (const short*)Wpk2;
    const short* Bg1 = (const short*)Wpk1;
    const short* Bg0 = (const short*)W2pk;

    int tile = blockIdx.x;
    int rbase0 = tile*128 + wave*32;
    // row pointers for the two 16-row groups (clamped)
    int r0 = rbase0 + m;            r0 = r0 < N_NODES ? r0 : N_NODES - 1;
    int r1 = rbase0 + 16 + m;       r1 = r1 < N_NODES ? r1 : N_NODES - 1;
    const short* Arow0 = (const short*)Xb + (size_t)r0 * 256;
    const short* Arow1 = (const short*)Xb + (size_t)r1 * 256;

    // ---- conv2: pre = [agg2|h1] @ W' ; B streamed from L2, 2 MFMAs per B
    floatx4 acc2[8][2];
    #pragma unroll
    for (int i = 0; i < 8; i++)
        #pragma unroll
        for (int rg = 0; rg < 2; rg++)
            #pragma unroll
            for (int r = 0; r < 4; r++) acc2[i][rg][r] = 0.f;
    #pragma unroll
    for (int ks = 0; ks < 8; ks++) {
        short8 a0 = *(const short8*)(Arow0 + ks*32 + quad*8);
        short8 a1 = *(const short8*)(Arow1 + ks*32 + quad*8);
        #pragma unroll
        for (int nt = 0; nt < 8; nt++) {
            short8 b = *(const short8*)&Bg2[((ks*8 + nt)*64 + lane)*8];
            acc2[nt][0] = __builtin_amdgcn_mfma_f32_16x16x32_bf16(a0, b, acc2[nt][0], 0, 0, 0);
            acc2[nt][1] = __builtin_amdgcn_mfma_f32_16x16x32_bf16(a1, b, acc2[nt][1], 0, 0, 0);
        }
    }
    // ---- h2 = tanh(pre + bl2) -> per-wave swizzled LDS (persists both passes)
    #pragma unroll
    for (int nt = 0; nt < 8; nt++) {
        float bl2v = bl2[nt*16 + c0];
        int cg = nt*2 + (c0 >> 3);
        #pragma unroll
        for (int rg = 0; rg < 2; rg++) {
            short* Hrg = Hw + rg*2048;
            #pragma unroll
            for (int r = 0; r < 4; r++) {
                int row = quad*4 + r;
                Hrg[row*128 + ((cg ^ row) << 3) + (c0 & 7)] =
                    (short)bfu(ftanh(acc2[nt][rg][r] + bl2v));
            }
        }
    }
    // ---- GEMM1 (two 8-col passes) + GEMM2 chunks
    floatx4 lacc[2];
    #pragma unroll
    for (int rg = 0; rg < 2; rg++)
        #pragma unroll
        for (int r = 0; r < 4; r++) lacc[rg][r] = 0.f;
    #pragma unroll
    for (int p = 0; p < 2; p++) {
        floatx4 acc1[8][2];
        #pragma unroll
        for (int i = 0; i < 8; i++)
            #pragma unroll
            for (int rg = 0; rg < 2; rg++)
                #pragma unroll
                for (int r = 0; r < 4; r++) acc1[i][rg][r] = 0.f;
        #pragma unroll
        for (int ks = 0; ks < 4; ks++) {
            short8 a0 = *(const short8*)&Hw[0*2048 + m*128 + (((ks*4 + quad) ^ m) << 3)];
            short8 a1 = *(const short8*)&Hw[1*2048 + m*128 + (((ks*4 + quad) ^ m) << 3)];
            #pragma unroll
            for (int ntl = 0; ntl < 8; ntl++) {
                int nt = p*8 + ntl;
                short8 b = *(const short8*)&Bg1[((ks*16 + nt)*64 + lane)*8];
                acc1[ntl][0] = __builtin_amdgcn_mfma_f32_16x16x32_bf16(a0, b, acc1[ntl][0], 0, 0, 0);
                acc1[ntl][1] = __builtin_amdgcn_mfma_f32_16x16x32_bf16(a1, b, acc1[ntl][1], 0, 0, 0);
            }
        }
        // t = tanh(acc1 + b1) streamed through mini-slice, 32 cols per chunk
        #pragma unroll
        for (int ch = 0; ch < 4; ch++) {
            short8 w2 = *(const short8*)&Bg0[((p*4 + ch)*64 + lane)*8];
            #pragma unroll
            for (int rg = 0; rg < 2; rg++) {
                #pragma unroll
                for (int l = 0; l < 2; l++) {
                    int ntl = ch*2 + l;
                    float b1v = b1[(p*8 + ntl)*16 + c0];
                    int lc = l*16 + c0;
                    #pragma unroll
                    for (int r = 0; r < 4; r++)
                        Tw[(quad*4 + r)*40 + lc] =
                            (short)bfu(ftanh(acc1[ntl][rg][r] + b1v));
                }
                short8 a = *(const short8*)&Tw[m*40 + quad*8];
                lacc[rg] = __builtin_amdgcn_mfma_f32_16x16x32_bf16(a, w2, lacc[rg], 0, 0, 0);
            }
        }
    }
    // ---- softmax across the 8 class lanes (per row-group)
    float b2v = (c0 < CDIM) ? b2[c0] : 0.f;
    #pragma unroll
    for (int rg = 0; rg < 2; rg++) {
        int rbase = rbase0 + rg*16 + quad*4;
        #pragma unroll
        for (int r = 0; r < 4; r++) {
            float v = lacc[rg][r] + b2v;
            float mval = (c0 < CDIM) ? v : -INFINITY;
            #pragma unroll
            for (int off = 1; off < 8; off <<= 1)
                mval = fmaxf(mval, __shfl_xor(mval, off));
            float e = (c0 < CDIM) ? __expf(v - mval) : 0.f;
            float ssum = e;
            #pragma unroll
            for (int off = 1; off < 8; off <<= 1)
                ssum += __shfl_xor(ssum, off);
            int rowg = rbase + r;
            if (c0 < CDIM && rowg < N_NODES)
                out[(size_t)rowg*CDIM + c0] = e / ssum;
        }
    }
}

extern "C" void kernel_launch(void* const* d_in, const int* in_sizes, int n_in,
                              void* d_out, int out_size, void* d_ws, size_t ws_size,
                              hipStream_t stream) {
    const float* x   = (const float*)d_in[0];
    const int*   ei  = (const int*)d_in[1];
    const float* Wl1 = (const float*)d_in[2];
    const float* bl1 = (const float*)d_in[3];
    const float* Wr1 = (const float*)d_in[4];
    const float* Wl2 = (const float*)d_in[5];
    const float* bl2 = (const float*)d_in[6];
    const float* Wr2 = (const float*)d_in[7];
    const float* W1  = (const float*)d_in[8];
    const float* b1  = (const float*)d_in[9];
    const float* W2  = (const float*)d_in[10];
    const float* b2  = (const float*)d_in[11];

    float* ws     = (float*)d_ws;
    float* part   = ws + OFF_PART;
    int*   deg    = (int*)(ws + OFF_DEG);
    float4* h0    = (float4*)(ws + OFF_H0);
    int*   ell    = (int*)(ws + OFF_ELL);
    int*   cntT   = (int*)(ws + OFF_CNTT);
    int2*  scratch= (int2*)(ws + OFF_SCR);
    __hip_bfloat16* Wpk2 = (__hip_bfloat16*)(ws + OFF_WPK2);
    __hip_bfloat16* Wpk1 = (__hip_bfloat16*)(ws + OFF_WPK1);
    __hip_bfloat16* W2pk = (__hip_bfloat16*)(ws + OFF_W2PK);
    __hip_bfloat16* Xb   = (__hip_bfloat16*)(ws + OFF_XB);

    statsPart_k<<<NB_STATS + NBLK_P1, 256, 0, stream>>>(x, part, ei, cntT, scratch);
    binNorm_k<<<NBUCK + NB_NODE, 256, 0, stream>>>(x, part, h0,
            Wl2, Wr2, W1, W2, Wpk2, Wpk1, W2pk, cntT, scratch, ell, deg);
    agg1conv1_k<<<NB_NODE, 256, 0, stream>>>(h0, deg, ell,
            Wl1, bl1, Wr1, Xb);
    agg2_k<<<N_NODES / 16, 256, 0, stream>>>(Xb, deg, ell);
    conv2mlp_k<<<NT128, 256, 0, stream>>>(Xb, Wpk2, bl2, Wpk1, b1, W2pk, b2,
            (float*)d_out);
}

// Round 8
// 210.573 us; speedup vs baseline: 1.1345x; 1.1345x over previous
//
#include <hip/hip_runtime.h>
#include <hip/hip_bf16.h>
#include <math.h>

#define N_NODES 100000
#define N_EDGES 600000
#define H 128
#define LH 256
#define CDIM 8
#define NB_STATS 256
#define NT128 ((N_NODES + 127) / 128)   // 782 (128-row tiles, fused kernel)
#define ELLW 64                          // fixed ELL width; P(deg>=64)~1e-40 for Poisson(6)
#define NB_NODE ((N_NODES + 255) / 256)  // 391 blocks carry node/normalize work

// --- two-level atomic-free binning (proven R4: -20us vs global atomics) ---
#define NBUCK 391                        // dst >> 8 ; 100000>>8 = 390 max
#define NBLK_P1 64
#define EPB (N_EDGES / NBLK_P1)          // 9375 edges per P1 block
#define CAP 72                           // per-(block,bucket) capacity; mean 24,
                                         // P(Poisson(24)>=72)~3e-14 x 25K cells

typedef __attribute__((ext_vector_type(8))) short short8;
typedef __attribute__((ext_vector_type(4))) float floatx4;

// ------------- workspace layout (4-byte words) -------------
#define OFF_PART   0                                  // 256*11 = 2816
#define OFF_DEG    2816                               // N_NODES
#define OFF_H0     (OFF_DEG + N_NODES)                // 102816, 16B aligned
#define OFF_ELL    (OFF_H0 + N_NODES*4)               // 502816, N_NODES*64 words
#define OFF_CNTT   (OFF_ELL + N_NODES*ELLW)           // 6902816, 391*64 words
#define OFF_SCR    (OFF_CNTT + NBUCK*NBLK_P1)         // 6927840, int2-aligned
#define OFF_WPK2   (OFF_SCR + NBUCK*NBLK_P1*CAP*2)    // 10531296, 16B aligned
#define OFF_WPK1   (OFF_WPK2 + 16384)
#define OFF_W2PK   (OFF_WPK1 + 16384)
#define OFF_XB     (OFF_W2PK + 2048)                  // 10566112, 16B aligned
// end = 10566112 + 12.8M words = 23.37M words ~= 93.5 MB (< 103 MB proven)

__device__ __forceinline__ float rot_c() { return cosf(1.57079632679489661923f); }
__device__ __forceinline__ float rot_s() { return sinf(1.57079632679489661923f); }
__device__ __forceinline__ float bfhi(unsigned v) { return __uint_as_float(v & 0xffff0000u); }
__device__ __forceinline__ float bflo(unsigned v) { return __uint_as_float(v << 16); }
__device__ __forceinline__ float bfs(short s) {
    return __uint_as_float(((unsigned)(unsigned short)s) << 16);
}
__device__ __forceinline__ unsigned short bfu(float f) {
    __hip_bfloat16 h = __float2bfloat16(f);
    return *(unsigned short*)&h;
}
// fast tanh: 1 - 2/(e^{2x}+1). Exact at +-inf (rcp(inf)=0), rel err ~1e-6.
__device__ __forceinline__ float ftanh(float x) {
    float e = __expf(2.0f * x);
    return 1.0f - 2.0f * __builtin_amdgcn_rcpf(e + 1.0f);
}

// ---------------- kernel A: stats partials (blocks 0..255) + P1 edge
// partition (blocks 256..319). No dependency between the two roles.
__global__ __launch_bounds__(256) void statsPart_k(const float* __restrict__ x,
        float* __restrict__ part, const int* __restrict__ ei,
        int* __restrict__ cntT, int2* __restrict__ scratch) {
    __shared__ float red[4][11];
    __shared__ int lcnt[NBUCK];
    int tid = threadIdx.x;

    if (blockIdx.x >= NB_STATS) {
        // ---- P1 role: partition 9375 edges into 391 buckets, LDS atomics only
        int blk = blockIdx.x - NB_STATS;
        for (int i = tid; i < NBUCK; i += 256) lcnt[i] = 0;
        __syncthreads();
        int base = blk * EPB;
        for (int e = base + tid; e < base + EPB; e += 256) {
            int s = ei[e], d = ei[N_EDGES + e];
            int b = d >> 8;
            int pos = atomicAdd(&lcnt[b], 1);          // LDS atomic
            scratch[(b * NBLK_P1 + blk) * CAP + pos] = make_int2(s, d);
        }
        __syncthreads();
        for (int i = tid; i < NBUCK; i += 256)
            cntT[i * NBLK_P1 + blk] = lcnt[i];
        return;
    }

    // ---- stats role (fixed stride: only NB_STATS blocks participate)
    const float c = rot_c(), sn = rot_s();
    float mn0 = INFINITY, mx0 = -INFINITY, mn1 = INFINITY, mx1 = -INFINITY;
    float s0 = 0.f, s1 = 0.f, sr0 = 0.f, sr1 = 0.f;
    float mxr0 = -INFINITY, mxr1 = -INFINITY, mxa = -INFINITY;
    for (int i = blockIdx.x * 256 + tid; i < N_NODES; i += NB_STATS * 256) {
        float x0 = x[3*i], x1 = x[3*i+1], a = x[3*i+2];
        float r0 = c*x0 - sn*x1;
        float r1 = sn*x0 + c*x1;
        mn0 = fminf(mn0, x0); mx0 = fmaxf(mx0, x0);
        mn1 = fminf(mn1, x1); mx1 = fmaxf(mx1, x1);
        s0 += x0; s1 += x1; sr0 += r0; sr1 += r1;
        mxr0 = fmaxf(mxr0, r0); mxr1 = fmaxf(mxr1, r1);
        mxa = fmaxf(mxa, a);
    }
    float vals[11] = {mn0, mx0, mn1, mx1, s0, s1, sr0, sr1, mxr0, mxr1, mxa};
    int lane = tid & 63, wave = tid >> 6;
    #pragma unroll
    for (int v = 0; v < 11; v++) {
        const int op = (v==0||v==2) ? 0 : (v>=4 && v<=7) ? 2 : 1;
        float val = vals[v];
        #pragma unroll
        for (int off = 32; off > 0; off >>= 1) {
            float o = __shfl_down(val, off);
            val = (op==0) ? fminf(val,o) : (op==1) ? fmaxf(val,o) : (val+o);
        }
        if (lane == 0) red[wave][v] = val;
    }
    __syncthreads();
    if (tid < 11) {
        int v = tid;
        int op = (v==0||v==2) ? 0 : (v>=4 && v<=7) ? 2 : 1;
        float a = red[0][v], b = red[1][v], cc = red[2][v], d = red[3][v];
        float r = (op==0) ? fminf(fminf(a,b), fminf(cc,d))
                : (op==1) ? fmaxf(fmaxf(a,b), fmaxf(cc,d))
                : (a + b + cc + d);
        part[blockIdx.x * 11 + v] = r;
    }
}

// ---------------- kernel B: P2 bucket->ELL binning (blocks 0..390) +
// normalize/pack (blocks 391..781). Both depend only on kernel A.
__global__ __launch_bounds__(256) void binNorm_k(const float* __restrict__ x,
        const float* __restrict__ part, float4* __restrict__ h0,
        const float* __restrict__ Wl2, const float* __restrict__ Wr2,
        const float* __restrict__ W1, const float* __restrict__ W2,
        __hip_bfloat16* __restrict__ Wpk2, __hip_bfloat16* __restrict__ Wpk1,
        __hip_bfloat16* __restrict__ W2pk,
        const int* __restrict__ cntT, const int2* __restrict__ scratch,
        int* __restrict__ ell, int* __restrict__ deg) {
    __shared__ int pref[NBLK_P1 + 1];
    __shared__ int ncnt[256];
    __shared__ float res[11];
    int tid = threadIdx.x;

    if (blockIdx.x < NBUCK) {
        // ---- P2 role: bin bucket b (256 nodes) into final ELL, LDS atomics only
        int b = blockIdx.x;
        ncnt[tid] = 0;
        if (tid < NBLK_P1) pref[tid + 1] = cntT[b * NBLK_P1 + tid];
        __syncthreads();
        if (tid == 0) {
            pref[0] = 0;
            int acc = 0;
            #pragma unroll 8
            for (int j = 0; j < NBLK_P1; j++) { acc += pref[j+1]; pref[j+1] = acc; }
        }
        __syncthreads();
        int T = pref[NBLK_P1];
        for (int f = tid; f < T; f += 256) {
            int lo = 0, hi = NBLK_P1;           // find j: pref[j] <= f < pref[j+1]
            while (hi - lo > 1) {
                int mid = (lo + hi) >> 1;
                if (pref[mid] <= f) lo = mid; else hi = mid;
            }
            int2 sd = scratch[(b * NBLK_P1 + lo) * CAP + (f - pref[lo])];
            int pos = atomicAdd(&ncnt[sd.y & 255], 1);   // LDS atomic
            ell[(sd.y << 6) + pos] = sd.x;
        }
        __syncthreads();
        int n = (b << 8) + tid;
        if (n < N_NODES) deg[n] = ncnt[tid];
        return;
    }

    // ---- normalize role
    int nb = blockIdx.x - NBUCK;
    int i = nb * 256 + tid;
    if (tid < 64) {
        const int ops[11] = {0,1,0,1,2,2,2,2,1,1,1};
        for (int v = 0; v < 11; v++) {
            float val = part[tid * 11 + v];
            #pragma unroll
            for (int p = 1; p < 4; p++) {
                float o = part[(tid + p*64) * 11 + v];
                val = (ops[v]==0) ? fminf(val,o) : (ops[v]==1) ? fmaxf(val,o) : (val+o);
            }
            #pragma unroll
            for (int off = 32; off > 0; off >>= 1) {
                float o = __shfl_down(val, off);
                val = (ops[v]==0) ? fminf(val,o) : (ops[v]==1) ? fmaxf(val,o) : (val+o);
            }
            if (tid == 0) res[v] = val;
        }
    }
    __syncthreads();
    int rotate = (res[3] - res[2]) > (res[1] - res[0]);
    float mean0 = (rotate ? res[6] : res[4]) / (float)N_NODES;
    float mean1 = (rotate ? res[7] : res[5]) / (float)N_NODES;
    float imx0  = 1.0f / (rotate ? res[8] : res[1]);
    float imx1  = 1.0f / (rotate ? res[9] : res[3]);
    float imxa  = 1.0f / res[10];

    if (i < N_NODES) {
        const float c = rot_c(), sn = rot_s();
        float x0 = x[3*i], x1 = x[3*i+1], a = x[3*i+2];
        float u0 = rotate ? (c*x0 - sn*x1) : x0;
        float u1 = rotate ? (sn*x0 + c*x1) : x1;
        h0[i] = make_float4((u0 - mean0) * imx0, (u1 - mean1) * imx1, a * imxa, 0.f);
    }
    int idx = i;
    if (idx < 32768) {                       // Wpk2[ks8][nt8][lane64][j8], K=256,N=128
        int j = idx & 7, lane = (idx >> 3) & 63, nt = (idx >> 9) & 7, ks = idx >> 12;
        int k = ks*32 + (lane >> 4)*8 + j;
        int n = nt*16 + (lane & 15);
        float v = (k < 128) ? Wl2[n*H + k] : Wr2[n*H + (k - 128)];
        Wpk2[idx] = __float2bfloat16(v);
    } else if (idx < 65536) {                // Wpk1[ks4][nt16][lane64][j8], K=128,N=256
        int i2 = idx - 32768;
        int j = i2 & 7, lane = (i2 >> 3) & 63, nt = (i2 >> 9) & 15, ks = i2 >> 13;
        int k = ks*32 + (lane >> 4)*8 + j;
        int n = nt*16 + (lane & 15);
        Wpk1[i2] = __float2bfloat16(W1[n*H + k]);
    } else if (idx < 69632) {                // W2pk[ks8][lane64][j8], K=256,N=16(8 real)
        int i3 = idx - 65536;
        int j = i3 & 7, lane = (i3 >> 3) & 63, ks = i3 >> 9;
        int k = ks*32 + (lane >> 4)*8 + j;
        int n = lane & 15;
        W2pk[i3] = __float2bfloat16((n < CDIM) ? W2[n*LH + k] : 0.f);
    }
}

// ---------------- fused agg1 + conv1 dense ----------------
__global__ __launch_bounds__(256) void agg1conv1_k(const float4* __restrict__ h0,
        const int* __restrict__ deg, const int* __restrict__ ell,
        const float* __restrict__ Wl1, const float* __restrict__ bl1,
        const float* __restrict__ Wr1, __hip_bfloat16* __restrict__ Xb) {
    __shared__ float wl[H*3], wr[H*3], bb[H];
    __shared__ float4 sa[256];
    int tid = threadIdx.x;
    for (int i = tid; i < H*3; i += 256) { wl[i] = Wl1[i]; wr[i] = Wr1[i]; }
    if (tid < H) bb[tid] = bl1[tid];
    int base = blockIdx.x * 256;
    int n = base + tid;
    float4 av = make_float4(0.f, 0.f, 0.f, 0.f);
    if (n < N_NODES) {
        int dg = deg[n];
        int start = n << 6, end = start + dg;
        float a0 = 0.f, a1 = 0.f, a2 = 0.f;
        int e = start;
        for (; e + 3 < end; e += 4) {
            int s0 = ell[e], s1 = ell[e+1], s2 = ell[e+2], s3 = ell[e+3];
            float4 v0 = h0[s0];
            float4 v1 = h0[s1];
            float4 v2 = h0[s2];
            float4 v3 = h0[s3];
            a0 += (v0.x + v1.x) + (v2.x + v3.x);
            a1 += (v0.y + v1.y) + (v2.y + v3.y);
            a2 += (v0.z + v1.z) + (v2.z + v3.z);
        }
        for (; e < end; e++) {
            float4 v = h0[ell[e]];
            a0 += v.x; a1 += v.y; a2 += v.z;
        }
        float inv = 1.0f / (float)max(dg, 1);
        av = make_float4(a0 * inv, a1 * inv, a2 * inv, 0.f);
    }
    sa[tid] = av;
    __syncthreads();
    int sub = tid >> 6;
    int j2 = (tid & 63) * 2;
    for (int i = 0; i < 64; i++) {
        int loc = i * 4 + sub;
        int nn = base + loc;
        if (nn >= N_NODES) break;
        float4 a = sa[loc];
        float4 xv = h0[nn];
        float o0 = wl[3*j2+0]*a.x + wl[3*j2+1]*a.y + wl[3*j2+2]*a.z + bb[j2]
                 + wr[3*j2+0]*xv.x + wr[3*j2+1]*xv.y + wr[3*j2+2]*xv.z;
        float o1 = wl[3*j2+3]*a.x + wl[3*j2+4]*a.y + wl[3*j2+5]*a.z + bb[j2+1]
                 + wr[3*j2+3]*xv.x + wr[3*j2+4]*xv.y + wr[3*j2+5]*xv.z;
        unsigned pv = ((unsigned)bfu(ftanh(o1)) << 16) | (unsigned)bfu(ftanh(o0));
        *(unsigned*)&Xb[(size_t)nn*256 + 128 + j2] = pv;
    }
}

// ---------------- FUSED agg2 + conv2 + MLP + softmax ----------------
// Reverted to the proven R4 structure (160KB LDS, 512 thr, 43.6us) — R5/R6/R7
// restructures all lost to it. New: agg2 is FUSED into the A-fragment build
// (each row's 4 lanes gather+average the neighbors' h1 slices directly into
// registers), deleting the agg2_k kernel and the Xb[0:128] round-trip.
// Numerics identical: same bf16 inputs averaged in fp32, rounded to bf16 at
// the same point agg2_k rounded.
__global__ __launch_bounds__(512, 1) void conv2mlp_k(const __hip_bfloat16* __restrict__ Xb,
        const int* __restrict__ deg, const int* __restrict__ ell,
        const __hip_bfloat16* __restrict__ Wpk2, const float* __restrict__ bl2,
        const __hip_bfloat16* __restrict__ Wpk1, const float* __restrict__ b1,
        const __hip_bfloat16* __restrict__ W2pk, const float* __restrict__ b2,
        float* __restrict__ out) {
    __shared__ short Ws2[32768];         // conv2 weights [ks8][nt8][lane64][j8]
    __shared__ short Ws1[32768];         // W1 weights [ks4][nt16][lane64][j8]
    __shared__ short Cs[8 * 16 * 128];   // per-wave 16x128 swizzled staging
    int tid = threadIdx.x;
    int lane = tid & 63, wave = tid >> 6;
    int quad = lane >> 4, m = lane & 15, c0 = lane & 15;
    {
        // 512 threads x 8 iters x 16 B = exactly 64 KB per array
        const float4* s2 = (const float4*)Wpk2;
        const float4* s1 = (const float4*)Wpk1;
        float4* d2 = (float4*)Ws2;
        float4* d1 = (float4*)Ws1;
        #pragma unroll
        for (int i = 0; i < 8; i++) {
            d2[tid + i*512] = s2[tid + i*512];
            d1[tid + i*512] = s1[tid + i*512];
        }
    }
    short8 w2f[8];
    #pragma unroll
    for (int ks = 0; ks < 8; ks++)
        w2f[ks] = *(const short8*)&W2pk[(ks*64 + lane)*8];
    float bl2r[8], b1r[16];
    #pragma unroll
    for (int nt = 0; nt < 8; nt++) bl2r[nt] = bl2[nt*16 + c0];
    #pragma unroll
    for (int nt = 0; nt < 16; nt++) b1r[nt] = b1[nt*16 + c0];
    float b2v = (c0 < CDIM) ? b2[c0] : 0.f;

    // ---- fused agg2 gather (issued before the barrier so loads overlap
    // the weight staging): lane (quad,m) owns cols quad*8+{0..7}+32ks of
    // its row's neighbor-mean; 4 x 16B loads per neighbor.
    int tile = blockIdx.x;
    int row = tile*128 + wave*16 + m;
    int rowL = row < N_NODES ? row : N_NODES - 1;
    const short* XbS = (const short*)Xb;
    int dg = deg[rowL];
    int estart = rowL << 6;
    float ga[32];
    #pragma unroll
    for (int i = 0; i < 32; i++) ga[i] = 0.f;
    int e = 0;
    for (; e + 1 < dg; e += 2) {
        int s0 = ell[estart + e], s1 = ell[estart + e + 1];
        const short* p0 = XbS + (size_t)s0*256 + 128 + quad*8;
        const short* p1 = XbS + (size_t)s1*256 + 128 + quad*8;
        #pragma unroll
        for (int ks = 0; ks < 4; ks++) {
            short8 v0 = *(const short8*)(p0 + ks*32);
            short8 v1 = *(const short8*)(p1 + ks*32);
            #pragma unroll
            for (int j = 0; j < 8; j++)
                ga[ks*8+j] += bfs(v0[j]) + bfs(v1[j]);
        }
    }
    if (e < dg) {
        int s0 = ell[estart + e];
        const short* p0 = XbS + (size_t)s0*256 + 128 + quad*8;
        #pragma unroll
        for (int ks = 0; ks < 4; ks++) {
            short8 v0 = *(const short8*)(p0 + ks*32);
            #pragma unroll
            for (int j = 0; j < 8; j++)
                ga[ks*8+j] += bfs(v0[j]);
        }
    }
    short8 areg[8];
    {
        float inv = 1.0f / (float)max(dg, 1);
        #pragma unroll
        for (int ks = 0; ks < 4; ks++) {
            short8 t;
            #pragma unroll
            for (int j = 0; j < 8; j++)
                t[j] = (short)bfu(ga[ks*8+j] * inv);
            areg[ks] = t;
        }
        const short* Arow = XbS + (size_t)rowL * 256;
        #pragma unroll
        for (int ks = 4; ks < 8; ks++)
            areg[ks] = *(const short8*)(Arow + ks*32 + quad*8);
    }
    __syncthreads();
    short* Tw = &Cs[wave * (16 * 128)];

    // ---- conv2: h2 = tanh([agg2|h1] @ W' + bl2)
    floatx4 acc2[8];
    #pragma unroll
    for (int i = 0; i < 8; i++)
        #pragma unroll
        for (int r = 0; r < 4; r++) acc2[i][r] = 0.f;
    #pragma unroll
    for (int ks = 0; ks < 8; ks++) {
        #pragma unroll
        for (int nt = 0; nt < 8; nt++) {
            short8 b = *(const short8*)&Ws2[((ks*8 + nt)*64 + lane)*8];
            acc2[nt] = __builtin_amdgcn_mfma_f32_16x16x32_bf16(areg[ks], b, acc2[nt], 0, 0, 0);
        }
    }
    #pragma unroll
    for (int nt = 0; nt < 8; nt++) {
        int cg = nt*2 + (c0 >> 3);
        #pragma unroll
        for (int r = 0; r < 4; r++) {
            int row2 = quad*4 + r;
            Tw[row2*128 + ((cg ^ row2) << 3) + (c0 & 7)] =
                (short)bfu(ftanh(acc2[nt][r] + bl2r[nt]));
        }
    }
    // ---- GEMM1: t_pre = h2 @ W1^T  (A from the slice just written)
    floatx4 acc1[16];
    #pragma unroll
    for (int i = 0; i < 16; i++)
        #pragma unroll
        for (int r = 0; r < 4; r++) acc1[i][r] = 0.f;
    #pragma unroll
    for (int ks = 0; ks < 4; ks++) {
        short8 a = *(const short8*)&Tw[m*128 + (((ks*4 + quad) ^ m) << 3)];
        #pragma unroll
        for (int nt = 0; nt < 16; nt++) {
            short8 b = *(const short8*)&Ws1[((ks*16 + nt)*64 + lane)*8];
            acc1[nt] = __builtin_amdgcn_mfma_f32_16x16x32_bf16(a, b, acc1[nt], 0, 0, 0);
        }
    }
    // ---- GEMM2 in 4 K-chunks through the (now dead) slice
    floatx4 lacc;
    #pragma unroll
    for (int r = 0; r < 4; r++) lacc[r] = 0.f;
    #pragma unroll
    for (int ch = 0; ch < 4; ch++) {
        #pragma unroll
        for (int ntl = 0; ntl < 4; ntl++) {
            int nt = ch*4 + ntl;
            int cg = ntl*2 + (c0 >> 3);
            #pragma unroll
            for (int r = 0; r < 4; r++) {
                int row2 = quad*4 + r;
                Tw[row2*128 + ((cg ^ row2) << 3) + (c0 & 7)] =
                    (short)bfu(ftanh(acc1[nt][r] + b1r[nt]));
            }
        }
        #pragma unroll
        for (int k2 = 0; k2 < 2; k2++) {
            short8 a = *(const short8*)&Tw[m*128 + (((k2*4 + quad) ^ m) << 3)];
            lacc = __builtin_amdgcn_mfma_f32_16x16x32_bf16(a, w2f[ch*2 + k2], lacc, 0, 0, 0);
        }
    }
    // ---- softmax across the 8 class lanes
    int rbase = tile*128 + wave*16 + quad*4;
    #pragma unroll
    for (int r = 0; r < 4; r++) {
        float v = lacc[r] + b2v;
        float mval = (c0 < CDIM) ? v : -INFINITY;
        #pragma unroll
        for (int off = 1; off < 8; off <<= 1)
            mval = fmaxf(mval, __shfl_xor(mval, off));
        float e2 = (c0 < CDIM) ? __expf(v - mval) : 0.f;
        float ssum = e2;
        #pragma unroll
        for (int off = 1; off < 8; off <<= 1)
            ssum += __shfl_xor(ssum, off);
        int rowg = rbase + r;
        if (c0 < CDIM && rowg < N_NODES)
            out[(size_t)rowg*CDIM + c0] = e2 / ssum;
    }
}

extern "C" void kernel_launch(void* const* d_in, const int* in_sizes, int n_in,
                              void* d_out, int out_size, void* d_ws, size_t ws_size,
                              hipStream_t stream) {
    const float* x   = (const float*)d_in[0];
    const int*   ei  = (const int*)d_in[1];
    const float* Wl1 = (const float*)d_in[2];
    const float* bl1 = (const float*)d_in[3];
    const float* Wr1 = (const float*)d_in[4];
    const float* Wl2 = (const float*)d_in[5];
    const float* bl2 = (const float*)d_in[6];
    const float* Wr2 = (const float*)d_in[7];
    const float* W1  = (const float*)d_in[8];
    const float* b1  = (const float*)d_in[9];
    const float* W2  = (const float*)d_in[10];
    const float* b2  = (const float*)d_in[11];

    float* ws     = (float*)d_ws;
    float* part   = ws + OFF_PART;
    int*   deg    = (int*)(ws + OFF_DEG);
    float4* h0    = (float4*)(ws + OFF_H0);
    int*   ell    = (int*)(ws + OFF_ELL);
    int*   cntT   = (int*)(ws + OFF_CNTT);
    int2*  scratch= (int2*)(ws + OFF_SCR);
    __hip_bfloat16* Wpk2 = (__hip_bfloat16*)(ws + OFF_WPK2);
    __hip_bfloat16* Wpk1 = (__hip_bfloat16*)(ws + OFF_WPK1);
    __hip_bfloat16* W2pk = (__hip_bfloat16*)(ws + OFF_W2PK);
    __hip_bfloat16* Xb   = (__hip_bfloat16*)(ws + OFF_XB);

    statsPart_k<<<NB_STATS + NBLK_P1, 256, 0, stream>>>(x, part, ei, cntT, scratch);
    binNorm_k<<<NBUCK + NB_NODE, 256, 0, stream>>>(x, part, h0,
            Wl2, Wr2, W1, W2, Wpk2, Wpk1, W2pk, cntT, scratch, ell, deg);
    agg1conv1_k<<<NB_NODE, 256, 0, stream>>>(h0, deg, ell,
            Wl1, bl1, Wr1, Xb);
    conv2mlp_k<<<NT128, 512, 0, stream>>>(Xb, deg, ell, Wpk2, bl2, Wpk1, b1,
            W2pk, b2, (float*)d_out);
}

// Round 9
// 204.713 us; speedup vs baseline: 1.1670x; 1.0286x over previous
//
#include <hip/hip_runtime.h>
#include <hip/hip_bf16.h>
#include <math.h>

#define N_NODES 100000
#define N_EDGES 600000
#define H 128
#define LH 256
#define CDIM 8
#define NB_STATS 256
#define NT128 ((N_NODES + 127) / 128)   // 782 (128-row tiles, fused kernel)
#define ELLW 64                          // fixed ELL width; P(deg>=64)~1e-40 for Poisson(6)
#define NB_NODE ((N_NODES + 255) / 256)  // 391 blocks carry node/normalize work

// --- two-level atomic-free binning (proven R4: -20us vs global atomics) ---
#define NBUCK 391                        // dst >> 8 ; 100000>>8 = 390 max
#define NBLK_P1 64
#define EPB (N_EDGES / NBLK_P1)          // 9375 edges per P1 block
#define CAP 72                           // per-(block,bucket) capacity; mean 24,
                                         // P(Poisson(24)>=72)~3e-14 x 25K cells

typedef __attribute__((ext_vector_type(8))) short short8;
typedef __attribute__((ext_vector_type(4))) float floatx4;

// ------------- workspace layout (4-byte words) -------------
#define OFF_PART   0                                  // 256*11 = 2816
#define OFF_DEG    2816                               // N_NODES
#define OFF_H0     (OFF_DEG + N_NODES)                // 102816, 16B aligned
#define OFF_ELL    (OFF_H0 + N_NODES*4)               // 502816, N_NODES*64 words
#define OFF_CNTT   (OFF_ELL + N_NODES*ELLW)           // 6902816, 391*64 words
#define OFF_SCR    (OFF_CNTT + NBUCK*NBLK_P1)         // 6927840, int2-aligned
#define OFF_WPK2   (OFF_SCR + NBUCK*NBLK_P1*CAP*2)    // 10531296, 16B aligned
#define OFF_WPK1   (OFF_WPK2 + 16384)
#define OFF_W2PK   (OFF_WPK1 + 16384)
#define OFF_XB     (OFF_W2PK + 2048)                  // 10566112, 16B aligned
// end = 10566112 + 12.8M words = 23.37M words ~= 93.5 MB (< 103 MB proven)

__device__ __forceinline__ float rot_c() { return cosf(1.57079632679489661923f); }
__device__ __forceinline__ float rot_s() { return sinf(1.57079632679489661923f); }
__device__ __forceinline__ float bfhi(unsigned v) { return __uint_as_float(v & 0xffff0000u); }
__device__ __forceinline__ float bflo(unsigned v) { return __uint_as_float(v << 16); }
__device__ __forceinline__ unsigned short bfu(float f) {
    __hip_bfloat16 h = __float2bfloat16(f);
    return *(unsigned short*)&h;
}
// fast tanh: 1 - 2/(e^{2x}+1). Exact at +-inf (rcp(inf)=0), rel err ~1e-6.
__device__ __forceinline__ float ftanh(float x) {
    float e = __expf(2.0f * x);
    return 1.0f - 2.0f * __builtin_amdgcn_rcpf(e + 1.0f);
}

// ---------------- kernel A: stats partials (blocks 0..255) + P1 edge
// partition (blocks 256..319). No dependency between the two roles.
__global__ __launch_bounds__(256) void statsPart_k(const float* __restrict__ x,
        float* __restrict__ part, const int* __restrict__ ei,
        int* __restrict__ cntT, int2* __restrict__ scratch) {
    __shared__ float red[4][11];
    __shared__ int lcnt[NBUCK];
    int tid = threadIdx.x;

    if (blockIdx.x >= NB_STATS) {
        // ---- P1 role: partition 9375 edges into 391 buckets, LDS atomics only
        int blk = blockIdx.x - NB_STATS;
        for (int i = tid; i < NBUCK; i += 256) lcnt[i] = 0;
        __syncthreads();
        int base = blk * EPB;
        for (int e = base + tid; e < base + EPB; e += 256) {
            int s = ei[e], d = ei[N_EDGES + e];
            int b = d >> 8;
            int pos = atomicAdd(&lcnt[b], 1);          // LDS atomic
            scratch[(b * NBLK_P1 + blk) * CAP + pos] = make_int2(s, d);
        }
        __syncthreads();
        for (int i = tid; i < NBUCK; i += 256)
            cntT[i * NBLK_P1 + blk] = lcnt[i];
        return;
    }

    // ---- stats role (fixed stride: only NB_STATS blocks participate)
    const float c = rot_c(), sn = rot_s();
    float mn0 = INFINITY, mx0 = -INFINITY, mn1 = INFINITY, mx1 = -INFINITY;
    float s0 = 0.f, s1 = 0.f, sr0 = 0.f, sr1 = 0.f;
    float mxr0 = -INFINITY, mxr1 = -INFINITY, mxa = -INFINITY;
    for (int i = blockIdx.x * 256 + tid; i < N_NODES; i += NB_STATS * 256) {
        float x0 = x[3*i], x1 = x[3*i+1], a = x[3*i+2];
        float r0 = c*x0 - sn*x1;
        float r1 = sn*x0 + c*x1;
        mn0 = fminf(mn0, x0); mx0 = fmaxf(mx0, x0);
        mn1 = fminf(mn1, x1); mx1 = fmaxf(mx1, x1);
        s0 += x0; s1 += x1; sr0 += r0; sr1 += r1;
        mxr0 = fmaxf(mxr0, r0); mxr1 = fmaxf(mxr1, r1);
        mxa = fmaxf(mxa, a);
    }
    float vals[11] = {mn0, mx0, mn1, mx1, s0, s1, sr0, sr1, mxr0, mxr1, mxa};
    int lane = tid & 63, wave = tid >> 6;
    #pragma unroll
    for (int v = 0; v < 11; v++) {
        const int op = (v==0||v==2) ? 0 : (v>=4 && v<=7) ? 2 : 1;
        float val = vals[v];
        #pragma unroll
        for (int off = 32; off > 0; off >>= 1) {
            float o = __shfl_down(val, off);
            val = (op==0) ? fminf(val,o) : (op==1) ? fmaxf(val,o) : (val+o);
        }
        if (lane == 0) red[wave][v] = val;
    }
    __syncthreads();
    if (tid < 11) {
        int v = tid;
        int op = (v==0||v==2) ? 0 : (v>=4 && v<=7) ? 2 : 1;
        float a = red[0][v], b = red[1][v], cc = red[2][v], d = red[3][v];
        float r = (op==0) ? fminf(fminf(a,b), fminf(cc,d))
                : (op==1) ? fmaxf(fmaxf(a,b), fmaxf(cc,d))
                : (a + b + cc + d);
        part[blockIdx.x * 11 + v] = r;
    }
}

// ---------------- kernel B: P2 bucket->ELL binning (blocks 0..390) +
// normalize/pack (blocks 391..781). Both depend only on kernel A.
__global__ __launch_bounds__(256) void binNorm_k(const float* __restrict__ x,
        const float* __restrict__ part, float4* __restrict__ h0,
        const float* __restrict__ Wl2, const float* __restrict__ Wr2,
        const float* __restrict__ W1, const float* __restrict__ W2,
        __hip_bfloat16* __restrict__ Wpk2, __hip_bfloat16* __restrict__ Wpk1,
        __hip_bfloat16* __restrict__ W2pk,
        const int* __restrict__ cntT, const int2* __restrict__ scratch,
        int* __restrict__ ell, int* __restrict__ deg) {
    __shared__ int pref[NBLK_P1 + 1];
    __shared__ int ncnt[256];
    __shared__ float res[11];
    int tid = threadIdx.x;

    if (blockIdx.x < NBUCK) {
        // ---- P2 role: bin bucket b (256 nodes) into final ELL, LDS atomics only
        int b = blockIdx.x;
        ncnt[tid] = 0;
        if (tid < NBLK_P1) pref[tid + 1] = cntT[b * NBLK_P1 + tid];
        __syncthreads();
        if (tid == 0) {
            pref[0] = 0;
            int acc = 0;
            #pragma unroll 8
            for (int j = 0; j < NBLK_P1; j++) { acc += pref[j+1]; pref[j+1] = acc; }
        }
        __syncthreads();
        int T = pref[NBLK_P1];
        for (int f = tid; f < T; f += 256) {
            int lo = 0, hi = NBLK_P1;           // find j: pref[j] <= f < pref[j+1]
            while (hi - lo > 1) {
                int mid = (lo + hi) >> 1;
                if (pref[mid] <= f) lo = mid; else hi = mid;
            }
            int2 sd = scratch[(b * NBLK_P1 + lo) * CAP + (f - pref[lo])];
            int pos = atomicAdd(&ncnt[sd.y & 255], 1);   // LDS atomic
            ell[(sd.y << 6) + pos] = sd.x;
        }
        __syncthreads();
        int n = (b << 8) + tid;
        if (n < N_NODES) deg[n] = ncnt[tid];
        return;
    }

    // ---- normalize role
    int nb = blockIdx.x - NBUCK;
    int i = nb * 256 + tid;
    if (tid < 64) {
        const int ops[11] = {0,1,0,1,2,2,2,2,1,1,1};
        for (int v = 0; v < 11; v++) {
            float val = part[tid * 11 + v];
            #pragma unroll
            for (int p = 1; p < 4; p++) {
                float o = part[(tid + p*64) * 11 + v];
                val = (ops[v]==0) ? fminf(val,o) : (ops[v]==1) ? fmaxf(val,o) : (val+o);
            }
            #pragma unroll
            for (int off = 32; off > 0; off >>= 1) {
                float o = __shfl_down(val, off);
                val = (ops[v]==0) ? fminf(val,o) : (ops[v]==1) ? fmaxf(val,o) : (val+o);
            }
            if (tid == 0) res[v] = val;
        }
    }
    __syncthreads();
    int rotate = (res[3] - res[2]) > (res[1] - res[0]);
    float mean0 = (rotate ? res[6] : res[4]) / (float)N_NODES;
    float mean1 = (rotate ? res[7] : res[5]) / (float)N_NODES;
    float imx0  = 1.0f / (rotate ? res[8] : res[1]);
    float imx1  = 1.0f / (rotate ? res[9] : res[3]);
    float imxa  = 1.0f / res[10];

    if (i < N_NODES) {
        const float c = rot_c(), sn = rot_s();
        float x0 = x[3*i], x1 = x[3*i+1], a = x[3*i+2];
        float u0 = rotate ? (c*x0 - sn*x1) : x0;
        float u1 = rotate ? (sn*x0 + c*x1) : x1;
        h0[i] = make_float4((u0 - mean0) * imx0, (u1 - mean1) * imx1, a * imxa, 0.f);
    }
    int idx = i;
    if (idx < 32768) {                       // Wpk2[ks8][nt8][lane64][j8], K=256,N=128
        int j = idx & 7, lane = (idx >> 3) & 63, nt = (idx >> 9) & 7, ks = idx >> 12;
        int k = ks*32 + (lane >> 4)*8 + j;
        int n = nt*16 + (lane & 15);
        float v = (k < 128) ? Wl2[n*H + k] : Wr2[n*H + (k - 128)];
        Wpk2[idx] = __float2bfloat16(v);
    } else if (idx < 65536) {                // Wpk1[ks4][nt16][lane64][j8], K=128,N=256
        int i2 = idx - 32768;
        int j = i2 & 7, lane = (i2 >> 3) & 63, nt = (i2 >> 9) & 15, ks = i2 >> 13;
        int k = ks*32 + (lane >> 4)*8 + j;
        int n = nt*16 + (lane & 15);
        Wpk1[i2] = __float2bfloat16(W1[n*H + k]);
    } else if (idx < 69632) {                // W2pk[ks8][lane64][j8], K=256,N=16(8 real)
        int i3 = idx - 65536;
        int j = i3 & 7, lane = (i3 >> 3) & 63, ks = i3 >> 9;
        int k = ks*32 + (lane >> 4)*8 + j;
        int n = lane & 15;
        W2pk[i3] = __float2bfloat16((n < CDIM) ? W2[n*LH + k] : 0.f);
    }
}

// ---------------- fused agg1 + conv1 dense ----------------
__global__ __launch_bounds__(256) void agg1conv1_k(const float4* __restrict__ h0,
        const int* __restrict__ deg, const int* __restrict__ ell,
        const float* __restrict__ Wl1, const float* __restrict__ bl1,
        const float* __restrict__ Wr1, __hip_bfloat16* __restrict__ Xb) {
    __shared__ float wl[H*3], wr[H*3], bb[H];
    __shared__ float4 sa[256];
    int tid = threadIdx.x;
    for (int i = tid; i < H*3; i += 256) { wl[i] = Wl1[i]; wr[i] = Wr1[i]; }
    if (tid < H) bb[tid] = bl1[tid];
    int base = blockIdx.x * 256;
    int n = base + tid;
    float4 av = make_float4(0.f, 0.f, 0.f, 0.f);
    if (n < N_NODES) {
        int dg = deg[n];
        int start = n << 6, end = start + dg;
        float a0 = 0.f, a1 = 0.f, a2 = 0.f;
        int e = start;
        for (; e + 3 < end; e += 4) {
            int s0 = ell[e], s1 = ell[e+1], s2 = ell[e+2], s3 = ell[e+3];
            float4 v0 = h0[s0];
            float4 v1 = h0[s1];
            float4 v2 = h0[s2];
            float4 v3 = h0[s3];
            a0 += (v0.x + v1.x) + (v2.x + v3.x);
            a1 += (v0.y + v1.y) + (v2.y + v3.y);
            a2 += (v0.z + v1.z) + (v2.z + v3.z);
        }
        for (; e < end; e++) {
            float4 v = h0[ell[e]];
            a0 += v.x; a1 += v.y; a2 += v.z;
        }
        float inv = 1.0f / (float)max(dg, 1);
        av = make_float4(a0 * inv, a1 * inv, a2 * inv, 0.f);
    }
    sa[tid] = av;
    __syncthreads();
    int sub = tid >> 6;
    int j2 = (tid & 63) * 2;
    for (int i = 0; i < 64; i++) {
        int loc = i * 4 + sub;
        int nn = base + loc;
        if (nn >= N_NODES) break;
        float4 a = sa[loc];
        float4 xv = h0[nn];
        float o0 = wl[3*j2+0]*a.x + wl[3*j2+1]*a.y + wl[3*j2+2]*a.z + bb[j2]
                 + wr[3*j2+0]*xv.x + wr[3*j2+1]*xv.y + wr[3*j2+2]*xv.z;
        float o1 = wl[3*j2+3]*a.x + wl[3*j2+4]*a.y + wl[3*j2+5]*a.z + bb[j2+1]
                 + wr[3*j2+3]*xv.x + wr[3*j2+4]*xv.y + wr[3*j2+5]*xv.z;
        unsigned pv = ((unsigned)bfu(ftanh(o1)) << 16) | (unsigned)bfu(ftanh(o0));
        *(unsigned*)&Xb[(size_t)nn*256 + 128 + j2] = pv;
    }
}

// ---------------- agg2: mean of h1 (bf16) -> Xb[n][0..127]
// 16 lanes/node x uint4 (16 B/lane); unroll-4 keeps 4 independent gathers in
// flight per lane (deg mean ~6 -> one 4-wide iter + remainder).
__global__ void agg2_k(__hip_bfloat16* __restrict__ Xb, const int* __restrict__ deg,
                       const int* __restrict__ ell) {
    int lane = threadIdx.x & 15;
    int n = blockIdx.x * 16 + (threadIdx.x >> 4);
    int dg = deg[n];
    int start = n << 6, end = start + dg;
    const short* XbS = (const short*)Xb;
    float a0=0.f,a1=0.f,a2=0.f,a3=0.f,a4=0.f,a5=0.f,a6=0.f,a7=0.f;
    int e = start;
    for (; e + 3 < end; e += 4) {
        int s0 = ell[e], s1 = ell[e+1], s2 = ell[e+2], s3 = ell[e+3];
        uint4 v0 = *(const uint4*)&XbS[(size_t)s0*256 + 128 + lane*8];
        uint4 v1 = *(const uint4*)&XbS[(size_t)s1*256 + 128 + lane*8];
        uint4 v2 = *(const uint4*)&XbS[(size_t)s2*256 + 128 + lane*8];
        uint4 v3 = *(const uint4*)&XbS[(size_t)s3*256 + 128 + lane*8];
        a0 += (bflo(v0.x) + bflo(v1.x)) + (bflo(v2.x) + bflo(v3.x));
        a1 += (bfhi(v0.x) + bfhi(v1.x)) + (bfhi(v2.x) + bfhi(v3.x));
        a2 += (bflo(v0.y) + bflo(v1.y)) + (bflo(v2.y) + bflo(v3.y));
        a3 += (bfhi(v0.y) + bfhi(v1.y)) + (bfhi(v2.y) + bfhi(v3.y));
        a4 += (bflo(v0.z) + bflo(v1.z)) + (bflo(v2.z) + bflo(v3.z));
        a5 += (bfhi(v0.z) + bfhi(v1.z)) + (bfhi(v2.z) + bfhi(v3.z));
        a6 += (bflo(v0.w) + bflo(v1.w)) + (bflo(v2.w) + bflo(v3.w));
        a7 += (bfhi(v0.w) + bfhi(v1.w)) + (bfhi(v2.w) + bfhi(v3.w));
    }
    for (; e < end; e++) {
        int s0 = ell[e];
        uint4 v0 = *(const uint4*)&XbS[(size_t)s0*256 + 128 + lane*8];
        a0 += bflo(v0.x); a1 += bfhi(v0.x);
        a2 += bflo(v0.y); a3 += bfhi(v0.y);
        a4 += bflo(v0.z); a5 += bfhi(v0.z);
        a6 += bflo(v0.w); a7 += bfhi(v0.w);
    }
    float inv = 1.0f / (float)max(dg, 1);
    uint4 o;
    o.x = ((unsigned)bfu(a1*inv) << 16) | (unsigned)bfu(a0*inv);
    o.y = ((unsigned)bfu(a3*inv) << 16) | (unsigned)bfu(a2*inv);
    o.z = ((unsigned)bfu(a5*inv) << 16) | (unsigned)bfu(a4*inv);
    o.w = ((unsigned)bfu(a7*inv) << 16) | (unsigned)bfu(a6*inv);
    *(uint4*)&Xb[(size_t)n*256 + lane*8] = o;
}

// ---------------- FUSED conv2 + MLP + softmax (proven R4 structure) -------
// 512 threads share Ws2+Ws1 (128 KB); per-wave 16x128 staging slice with XOR
// swizzle; 160 KB LDS = 1 block/CU; persistent 256 blocks with A-prefetch.
__global__ __launch_bounds__(512, 1) void conv2mlp_k(const __hip_bfloat16* __restrict__ Xb,
        const __hip_bfloat16* __restrict__ Wpk2, const float* __restrict__ bl2,
        const __hip_bfloat16* __restrict__ Wpk1, const float* __restrict__ b1,
        const __hip_bfloat16* __restrict__ W2pk, const float* __restrict__ b2,
        float* __restrict__ out) {
    __shared__ short Ws2[32768];         // conv2 weights [ks8][nt8][lane64][j8]
    __shared__ short Ws1[32768];         // W1 weights [ks4][nt16][lane64][j8]
    __shared__ short Cs[8 * 16 * 128];   // per-wave 16x128 swizzled staging
    int tid = threadIdx.x;
    int lane = tid & 63, wave = tid >> 6;
    int quad = lane >> 4, m = lane & 15, c0 = lane & 15;
    {
        const float4* s2 = (const float4*)Wpk2;
        const float4* s1 = (const float4*)Wpk1;
        float4* d2 = (float4*)Ws2;
        float4* d1 = (float4*)Ws1;
        #pragma unroll
        for (int i = 0; i < 8; i++) {
            d2[tid + i*512] = s2[tid + i*512];
            d1[tid + i*512] = s1[tid + i*512];
        }
    }
    short8 w2f[8];
    #pragma unroll
    for (int ks = 0; ks < 8; ks++)
        w2f[ks] = *(const short8*)&W2pk[(ks*64 + lane)*8];
    float bl2r[8], b1r[16];
    #pragma unroll
    for (int nt = 0; nt < 8; nt++) bl2r[nt] = bl2[nt*16 + c0];
    #pragma unroll
    for (int nt = 0; nt < 16; nt++) b1r[nt] = b1[nt*16 + c0];
    float b2v = (c0 < CDIM) ? b2[c0] : 0.f;
    __syncthreads();
    short* Tw = &Cs[wave * (16 * 128)];

    int tile = blockIdx.x;
    short8 areg[8];
    {
        int row = tile*128 + wave*16 + m;
        int rowL = row < N_NODES ? row : N_NODES - 1;
        const short* Arow = (const short*)Xb + (size_t)rowL * 256;
        #pragma unroll
        for (int ks = 0; ks < 8; ks++)
            areg[ks] = *(const short8*)(Arow + ks*32 + quad*8);
    }
    for (; tile < NT128; tile += gridDim.x) {
        short8 anext[8];
        {
            int tnext = tile + gridDim.x;
            int rown = (tnext < NT128) ? (tnext*128 + wave*16 + m) : 0;
            int rowNL = rown < N_NODES ? rown : N_NODES - 1;
            const short* ArowN = (const short*)Xb + (size_t)rowNL * 256;
            #pragma unroll
            for (int ks = 0; ks < 8; ks++)
                anext[ks] = *(const short8*)(ArowN + ks*32 + quad*8);
        }
        // ---- conv2: h2 = tanh([agg2|h1] @ W' + bl2)
        floatx4 acc2[8];
        #pragma unroll
        for (int i = 0; i < 8; i++)
            #pragma unroll
            for (int r = 0; r < 4; r++) acc2[i][r] = 0.f;
        #pragma unroll
        for (int ks = 0; ks < 8; ks++) {
            #pragma unroll
            for (int nt = 0; nt < 8; nt++) {
                short8 b = *(const short8*)&Ws2[((ks*8 + nt)*64 + lane)*8];
                acc2[nt] = __builtin_amdgcn_mfma_f32_16x16x32_bf16(areg[ks], b, acc2[nt], 0, 0, 0);
            }
        }
        #pragma unroll
        for (int nt = 0; nt < 8; nt++) {
            int cg = nt*2 + (c0 >> 3);
            #pragma unroll
            for (int r = 0; r < 4; r++) {
                int row = quad*4 + r;
                Tw[row*128 + ((cg ^ row) << 3) + (c0 & 7)] =
                    (short)bfu(ftanh(acc2[nt][r] + bl2r[nt]));
            }
        }
        // ---- GEMM1: t_pre = h2 @ W1^T  (A from the slice just written)
        floatx4 acc1[16];
        #pragma unroll
        for (int i = 0; i < 16; i++)
            #pragma unroll
            for (int r = 0; r < 4; r++) acc1[i][r] = 0.f;
        #pragma unroll
        for (int ks = 0; ks < 4; ks++) {
            short8 a = *(const short8*)&Tw[m*128 + (((ks*4 + quad) ^ m) << 3)];
            #pragma unroll
            for (int nt = 0; nt < 16; nt++) {
                short8 b = *(const short8*)&Ws1[((ks*16 + nt)*64 + lane)*8];
                acc1[nt] = __builtin_amdgcn_mfma_f32_16x16x32_bf16(a, b, acc1[nt], 0, 0, 0);
            }
        }
        // ---- GEMM2 in 4 K-chunks through the (now dead) slice
        floatx4 lacc;
        #pragma unroll
        for (int r = 0; r < 4; r++) lacc[r] = 0.f;
        #pragma unroll
        for (int ch = 0; ch < 4; ch++) {
            #pragma unroll
            for (int ntl = 0; ntl < 4; ntl++) {
                int nt = ch*4 + ntl;
                int cg = ntl*2 + (c0 >> 3);
                #pragma unroll
                for (int r = 0; r < 4; r++) {
                    int row = quad*4 + r;
                    Tw[row*128 + ((cg ^ row) << 3) + (c0 & 7)] =
                        (short)bfu(ftanh(acc1[nt][r] + b1r[nt]));
                }
            }
            #pragma unroll
            for (int k2 = 0; k2 < 2; k2++) {
                short8 a = *(const short8*)&Tw[m*128 + (((k2*4 + quad) ^ m) << 3)];
                lacc = __builtin_amdgcn_mfma_f32_16x16x32_bf16(a, w2f[ch*2 + k2], lacc, 0, 0, 0);
            }
        }
        // ---- softmax across the 8 class lanes
        int rbase = tile*128 + wave*16 + quad*4;
        #pragma unroll
        for (int r = 0; r < 4; r++) {
            float v = lacc[r] + b2v;
            float mval = (c0 < CDIM) ? v : -INFINITY;
            #pragma unroll
            for (int off = 1; off < 8; off <<= 1)
                mval = fmaxf(mval, __shfl_xor(mval, off));
            float e = (c0 < CDIM) ? __expf(v - mval) : 0.f;
            float ssum = e;
            #pragma unroll
            for (int off = 1; off < 8; off <<= 1)
                ssum += __shfl_xor(ssum, off);
            int rowg = rbase + r;
            if (c0 < CDIM && rowg < N_NODES)
                out[(size_t)rowg*CDIM + c0] = e / ssum;
        }
        #pragma unroll
        for (int ks = 0; ks < 8; ks++) areg[ks] = anext[ks];
    }
}

extern "C" void kernel_launch(void* const* d_in, const int* in_sizes, int n_in,
                              void* d_out, int out_size, void* d_ws, size_t ws_size,
                              hipStream_t stream) {
    const float* x   = (const float*)d_in[0];
    const int*   ei  = (const int*)d_in[1];
    const float* Wl1 = (const float*)d_in[2];
    const float* bl1 = (const float*)d_in[3];
    const float* Wr1 = (const float*)d_in[4];
    const float* Wl2 = (const float*)d_in[5];
    const float* bl2 = (const float*)d_in[6];
    const float* Wr2 = (const float*)d_in[7];
    const float* W1  = (const float*)d_in[8];
    const float* b1  = (const float*)d_in[9];
    const float* W2  = (const float*)d_in[10];
    const float* b2  = (const float*)d_in[11];

    float* ws     = (float*)d_ws;
    float* part   = ws + OFF_PART;
    int*   deg    = (int*)(ws + OFF_DEG);
    float4* h0    = (float4*)(ws + OFF_H0);
    int*   ell    = (int*)(ws + OFF_ELL);
    int*   cntT   = (int*)(ws + OFF_CNTT);
    int2*  scratch= (int2*)(ws + OFF_SCR);
    __hip_bfloat16* Wpk2 = (__hip_bfloat16*)(ws + OFF_WPK2);
    __hip_bfloat16* Wpk1 = (__hip_bfloat16*)(ws + OFF_WPK1);
    __hip_bfloat16* W2pk = (__hip_bfloat16*)(ws + OFF_W2PK);
    __hip_bfloat16* Xb   = (__hip_bfloat16*)(ws + OFF_XB);

    statsPart_k<<<NB_STATS + NBLK_P1, 256, 0, stream>>>(x, part, ei, cntT, scratch);
    binNorm_k<<<NBUCK + NB_NODE, 256, 0, stream>>>(x, part, h0,
            Wl2, Wr2, W1, W2, Wpk2, Wpk1, W2pk, cntT, scratch, ell, deg);
    agg1conv1_k<<<NB_NODE, 256, 0, stream>>>(h0, deg, ell,
            Wl1, bl1, Wr1, Xb);
    agg2_k<<<N_NODES / 16, 256, 0, stream>>>(Xb, deg, ell);
    conv2mlp_k<<<256, 512, 0, stream>>>(Xb, Wpk2, bl2, Wpk1, b1, W2pk, b2,
            (float*)d_out);
}

// Round 10
// 196.279 us; speedup vs baseline: 1.2171x; 1.0430x over previous
//
#include <hip/hip_runtime.h>
#include <hip/hip_bf16.h>
#include <math.h>

#define N_NODES 100000
#define N_EDGES 600000
#define H 128
#define LH 256
#define CDIM 8
#define NB_STATS 256
#define NT128 ((N_NODES + 127) / 128)   // 782 (128-row tiles, fused kernel)
#define ELLW 64                          // fixed ELL width; P(deg>=64)~1e-40 for Poisson(6)
#define NB_NODE ((N_NODES + 255) / 256)  // 391 blocks carry node/normalize work

// --- two-level atomic-free binning (proven R4: -20us vs global atomics) ---
// R9 post-mortem: P1 ran on only 64 blocks (1 wave/CU) -> serial-latency
// bound. NBLK_P1 64->256 (9 edges/thread, 8 waves/CU); CAP 72->26
// (mean 6/cell, P(Poisson(6)>=26)~1.6e-12 x 100K cells — safe).
#define NBUCK 391                        // dst >> 8 ; 100000>>8 = 390 max
#define NBLK_P1 256
#define EPB ((N_EDGES + NBLK_P1 - 1) / NBLK_P1)   // 2344 edges per P1 block
#define CAP 26

typedef __attribute__((ext_vector_type(8))) short short8;
typedef __attribute__((ext_vector_type(4))) float floatx4;

// ------------- workspace layout (4-byte words) -------------
#define OFF_PART   0                                  // 256*11 = 2816
#define OFF_DEG    2816                               // N_NODES
#define OFF_H0     (OFF_DEG + N_NODES)                // 102816, 16B aligned
#define OFF_ELL    (OFF_H0 + N_NODES*4)               // 502816, N_NODES*64 words
#define OFF_CNTT   (OFF_ELL + N_NODES*ELLW)           // 6902816, 391*256 words
#define OFF_SCR    (OFF_CNTT + NBUCK*NBLK_P1)         // 7002912, int2-aligned
#define OFF_WPK2   (OFF_SCR + NBUCK*NBLK_P1*CAP*2)    // 12207904, 16B aligned
#define OFF_WPK1   (OFF_WPK2 + 16384)
#define OFF_W2PK   (OFF_WPK1 + 16384)
#define OFF_XB     (OFF_W2PK + 2048)                  // 12242720, 16B aligned
// end = 12242720 + 12.8M words = 25.04M words ~= 100.2 MB (< 103 MB proven)

__device__ __forceinline__ float rot_c() { return cosf(1.57079632679489661923f); }
__device__ __forceinline__ float rot_s() { return sinf(1.57079632679489661923f); }
__device__ __forceinline__ float bfhi(unsigned v) { return __uint_as_float(v & 0xffff0000u); }
__device__ __forceinline__ float bflo(unsigned v) { return __uint_as_float(v << 16); }
__device__ __forceinline__ unsigned short bfu(float f) {
    __hip_bfloat16 h = __float2bfloat16(f);
    return *(unsigned short*)&h;
}
// fast tanh: 1 - 2/(e^{2x}+1). Exact at +-inf (rcp(inf)=0), rel err ~1e-6.
__device__ __forceinline__ float ftanh(float x) {
    float e = __expf(2.0f * x);
    return 1.0f - 2.0f * __builtin_amdgcn_rcpf(e + 1.0f);
}

// ---------------- kernel A: stats partials (blocks 0..255) + P1 edge
// partition (blocks 256..511). No dependency between the two roles.
__global__ __launch_bounds__(256) void statsPart_k(const float* __restrict__ x,
        float* __restrict__ part, const int* __restrict__ ei,
        int* __restrict__ cntT, int2* __restrict__ scratch) {
    __shared__ float red[4][11];
    __shared__ int lcnt[NBUCK];
    int tid = threadIdx.x;

    if (blockIdx.x >= NB_STATS) {
        // ---- P1 role: partition ~2344 edges into 391 buckets, LDS atomics only
        int blk = blockIdx.x - NB_STATS;
        for (int i = tid; i < NBUCK; i += 256) lcnt[i] = 0;
        __syncthreads();
        int base = blk * EPB;
        int lim = base + EPB;
        if (lim > N_EDGES) lim = N_EDGES;
        for (int e = base + tid; e < lim; e += 256) {
            int s = ei[e], d = ei[N_EDGES + e];
            int b = d >> 8;
            int pos = atomicAdd(&lcnt[b], 1);          // LDS atomic
            scratch[(b * NBLK_P1 + blk) * CAP + pos] = make_int2(s, d);
        }
        __syncthreads();
        for (int i = tid; i < NBUCK; i += 256)
            cntT[i * NBLK_P1 + blk] = lcnt[i];
        return;
    }

    // ---- stats role (fixed stride: only NB_STATS blocks participate)
    const float c = rot_c(), sn = rot_s();
    float mn0 = INFINITY, mx0 = -INFINITY, mn1 = INFINITY, mx1 = -INFINITY;
    float s0 = 0.f, s1 = 0.f, sr0 = 0.f, sr1 = 0.f;
    float mxr0 = -INFINITY, mxr1 = -INFINITY, mxa = -INFINITY;
    for (int i = blockIdx.x * 256 + tid; i < N_NODES; i += NB_STATS * 256) {
        float x0 = x[3*i], x1 = x[3*i+1], a = x[3*i+2];
        float r0 = c*x0 - sn*x1;
        float r1 = sn*x0 + c*x1;
        mn0 = fminf(mn0, x0); mx0 = fmaxf(mx0, x0);
        mn1 = fminf(mn1, x1); mx1 = fmaxf(mx1, x1);
        s0 += x0; s1 += x1; sr0 += r0; sr1 += r1;
        mxr0 = fmaxf(mxr0, r0); mxr1 = fmaxf(mxr1, r1);
        mxa = fmaxf(mxa, a);
    }
    float vals[11] = {mn0, mx0, mn1, mx1, s0, s1, sr0, sr1, mxr0, mxr1, mxa};
    int lane = tid & 63, wave = tid >> 6;
    #pragma unroll
    for (int v = 0; v < 11; v++) {
        const int op = (v==0||v==2) ? 0 : (v>=4 && v<=7) ? 2 : 1;
        float val = vals[v];
        #pragma unroll
        for (int off = 32; off > 0; off >>= 1) {
            float o = __shfl_down(val, off);
            val = (op==0) ? fminf(val,o) : (op==1) ? fmaxf(val,o) : (val+o);
        }
        if (lane == 0) red[wave][v] = val;
    }
    __syncthreads();
    if (tid < 11) {
        int v = tid;
        int op = (v==0||v==2) ? 0 : (v>=4 && v<=7) ? 2 : 1;
        float a = red[0][v], b = red[1][v], cc = red[2][v], d = red[3][v];
        float r = (op==0) ? fminf(fminf(a,b), fminf(cc,d))
                : (op==1) ? fmaxf(fmaxf(a,b), fmaxf(cc,d))
                : (a + b + cc + d);
        part[blockIdx.x * 11 + v] = r;
    }
}

// ---------------- kernel B: P2 bucket->ELL binning (blocks 0..390) +
// normalize/pack (blocks 391..781). Both depend only on kernel A.
__global__ __launch_bounds__(256) void binNorm_k(const float* __restrict__ x,
        const float* __restrict__ part, float4* __restrict__ h0,
        const float* __restrict__ Wl2, const float* __restrict__ Wr2,
        const float* __restrict__ W1, const float* __restrict__ W2,
        __hip_bfloat16* __restrict__ Wpk2, __hip_bfloat16* __restrict__ Wpk1,
        __hip_bfloat16* __restrict__ W2pk,
        const int* __restrict__ cntT, const int2* __restrict__ scratch,
        int* __restrict__ ell, int* __restrict__ deg) {
    __shared__ int pref[NBLK_P1 + 1];
    __shared__ int scn[NBLK_P1];
    __shared__ int ncnt[256];
    __shared__ float res[11];
    int tid = threadIdx.x;

    if (blockIdx.x < NBUCK) {
        // ---- P2 role: bin bucket b (256 nodes) into final ELL, LDS atomics only
        int b = blockIdx.x;
        ncnt[tid] = 0;
        scn[tid] = cntT[b * NBLK_P1 + tid];       // 256 counts, one per thread
        __syncthreads();
        // Hillis-Steele inclusive scan over 256 (parallel; was serial tid0)
        for (int off = 1; off < NBLK_P1; off <<= 1) {
            int v = (tid >= off) ? scn[tid - off] : 0;
            __syncthreads();
            scn[tid] += v;
            __syncthreads();
        }
        if (tid == 0) pref[0] = 0;
        pref[tid + 1] = scn[tid];
        __syncthreads();
        int T = pref[NBLK_P1];
        for (int f = tid; f < T; f += 256) {
            int lo = 0, hi = NBLK_P1;           // find j: pref[j] <= f < pref[j+1]
            while (hi - lo > 1) {
                int mid = (lo + hi) >> 1;
                if (pref[mid] <= f) lo = mid; else hi = mid;
            }
            int2 sd = scratch[(b * NBLK_P1 + lo) * CAP + (f - pref[lo])];
            int pos = atomicAdd(&ncnt[sd.y & 255], 1);   // LDS atomic
            ell[(sd.y << 6) + pos] = sd.x;
        }
        __syncthreads();
        int n = (b << 8) + tid;
        if (n < N_NODES) deg[n] = ncnt[tid];
        return;
    }

    // ---- normalize role
    int nb = blockIdx.x - NBUCK;
    int i = nb * 256 + tid;
    if (tid < 64) {
        const int ops[11] = {0,1,0,1,2,2,2,2,1,1,1};
        for (int v = 0; v < 11; v++) {
            float val = part[tid * 11 + v];
            #pragma unroll
            for (int p = 1; p < 4; p++) {
                float o = part[(tid + p*64) * 11 + v];
                val = (ops[v]==0) ? fminf(val,o) : (ops[v]==1) ? fmaxf(val,o) : (val+o);
            }
            #pragma unroll
            for (int off = 32; off > 0; off >>= 1) {
                float o = __shfl_down(val, off);
                val = (ops[v]==0) ? fminf(val,o) : (ops[v]==1) ? fmaxf(val,o) : (val+o);
            }
            if (tid == 0) res[v] = val;
        }
    }
    __syncthreads();
    int rotate = (res[3] - res[2]) > (res[1] - res[0]);
    float mean0 = (rotate ? res[6] : res[4]) / (float)N_NODES;
    float mean1 = (rotate ? res[7] : res[5]) / (float)N_NODES;
    float imx0  = 1.0f / (rotate ? res[8] : res[1]);
    float imx1  = 1.0f / (rotate ? res[9] : res[3]);
    float imxa  = 1.0f / res[10];

    if (i < N_NODES) {
        const float c = rot_c(), sn = rot_s();
        float x0 = x[3*i], x1 = x[3*i+1], a = x[3*i+2];
        float u0 = rotate ? (c*x0 - sn*x1) : x0;
        float u1 = rotate ? (sn*x0 + c*x1) : x1;
        h0[i] = make_float4((u0 - mean0) * imx0, (u1 - mean1) * imx1, a * imxa, 0.f);
    }
    int idx = i;
    if (idx < 32768) {                       // Wpk2[ks8][nt8][lane64][j8], K=256,N=128
        int j = idx & 7, lane = (idx >> 3) & 63, nt = (idx >> 9) & 7, ks = idx >> 12;
        int k = ks*32 + (lane >> 4)*8 + j;
        int n = nt*16 + (lane & 15);
        float v = (k < 128) ? Wl2[n*H + k] : Wr2[n*H + (k - 128)];
        Wpk2[idx] = __float2bfloat16(v);
    } else if (idx < 65536) {                // Wpk1[ks4][nt16][lane64][j8], K=128,N=256
        int i2 = idx - 32768;
        int j = i2 & 7, lane = (i2 >> 3) & 63, nt = (i2 >> 9) & 15, ks = i2 >> 13;
        int k = ks*32 + (lane >> 4)*8 + j;
        int n = nt*16 + (lane & 15);
        Wpk1[i2] = __float2bfloat16(W1[n*H + k]);
    } else if (idx < 69632) {                // W2pk[ks8][lane64][j8], K=256,N=16(8 real)
        int i3 = idx - 65536;
        int j = i3 & 7, lane = (i3 >> 3) & 63, ks = i3 >> 9;
        int k = ks*32 + (lane >> 4)*8 + j;
        int n = lane & 15;
        W2pk[i3] = __float2bfloat16((n < CDIM) ? W2[n*LH + k] : 0.f);
    }
}

// ---------------- fused agg1 + conv1 dense ----------------
__global__ __launch_bounds__(256) void agg1conv1_k(const float4* __restrict__ h0,
        const int* __restrict__ deg, const int* __restrict__ ell,
        const float* __restrict__ Wl1, const float* __restrict__ bl1,
        const float* __restrict__ Wr1, __hip_bfloat16* __restrict__ Xb) {
    __shared__ float wl[H*3], wr[H*3], bb[H];
    __shared__ float4 sa[256];
    int tid = threadIdx.x;
    for (int i = tid; i < H*3; i += 256) { wl[i] = Wl1[i]; wr[i] = Wr1[i]; }
    if (tid < H) bb[tid] = bl1[tid];
    int base = blockIdx.x * 256;
    int n = base + tid;
    float4 av = make_float4(0.f, 0.f, 0.f, 0.f);
    if (n < N_NODES) {
        int dg = deg[n];
        int start = n << 6, end = start + dg;
        float a0 = 0.f, a1 = 0.f, a2 = 0.f;
        int e = start;
        for (; e + 3 < end; e += 4) {
            int s0 = ell[e], s1 = ell[e+1], s2 = ell[e+2], s3 = ell[e+3];
            float4 v0 = h0[s0];
            float4 v1 = h0[s1];
            float4 v2 = h0[s2];
            float4 v3 = h0[s3];
            a0 += (v0.x + v1.x) + (v2.x + v3.x);
            a1 += (v0.y + v1.y) + (v2.y + v3.y);
            a2 += (v0.z + v1.z) + (v2.z + v3.z);
        }
        for (; e < end; e++) {
            float4 v = h0[ell[e]];
            a0 += v.x; a1 += v.y; a2 += v.z;
        }
        float inv = 1.0f / (float)max(dg, 1);
        av = make_float4(a0 * inv, a1 * inv, a2 * inv, 0.f);
    }
    sa[tid] = av;
    __syncthreads();
    int sub = tid >> 6;
    int j2 = (tid & 63) * 2;
    for (int i = 0; i < 64; i++) {
        int loc = i * 4 + sub;
        int nn = base + loc;
        if (nn >= N_NODES) break;
        float4 a = sa[loc];
        float4 xv = h0[nn];
        float o0 = wl[3*j2+0]*a.x + wl[3*j2+1]*a.y + wl[3*j2+2]*a.z + bb[j2]
                 + wr[3*j2+0]*xv.x + wr[3*j2+1]*xv.y + wr[3*j2+2]*xv.z;
        float o1 = wl[3*j2+3]*a.x + wl[3*j2+4]*a.y + wl[3*j2+5]*a.z + bb[j2+1]
                 + wr[3*j2+3]*xv.x + wr[3*j2+4]*xv.y + wr[3*j2+5]*xv.z;
        unsigned pv = ((unsigned)bfu(ftanh(o1)) << 16) | (unsigned)bfu(ftanh(o0));
        *(unsigned*)&Xb[(size_t)nn*256 + 128 + j2] = pv;
    }
}

// ---------------- agg2: mean of h1 (bf16) -> Xb[n][0..127]
// 16 lanes/node x uint4 (16 B/lane); unroll-4 keeps 4 independent gathers in
// flight per lane (deg mean ~6 -> one 4-wide iter + remainder).
__global__ void agg2_k(__hip_bfloat16* __restrict__ Xb, const int* __restrict__ deg,
                       const int* __restrict__ ell) {
    int lane = threadIdx.x & 15;
    int n = blockIdx.x * 16 + (threadIdx.x >> 4);
    int dg = deg[n];
    int start = n << 6, end = start + dg;
    const short* XbS = (const short*)Xb;
    float a0=0.f,a1=0.f,a2=0.f,a3=0.f,a4=0.f,a5=0.f,a6=0.f,a7=0.f;
    int e = start;
    for (; e + 3 < end; e += 4) {
        int s0 = ell[e], s1 = ell[e+1], s2 = ell[e+2], s3 = ell[e+3];
        uint4 v0 = *(const uint4*)&XbS[(size_t)s0*256 + 128 + lane*8];
        uint4 v1 = *(const uint4*)&XbS[(size_t)s1*256 + 128 + lane*8];
        uint4 v2 = *(const uint4*)&XbS[(size_t)s2*256 + 128 + lane*8];
        uint4 v3 = *(const uint4*)&XbS[(size_t)s3*256 + 128 + lane*8];
        a0 += (bflo(v0.x) + bflo(v1.x)) + (bflo(v2.x) + bflo(v3.x));
        a1 += (bfhi(v0.x) + bfhi(v1.x)) + (bfhi(v2.x) + bfhi(v3.x));
        a2 += (bflo(v0.y) + bflo(v1.y)) + (bflo(v2.y) + bflo(v3.y));
        a3 += (bfhi(v0.y) + bfhi(v1.y)) + (bfhi(v2.y) + bfhi(v3.y));
        a4 += (bflo(v0.z) + bflo(v1.z)) + (bflo(v2.z) + bflo(v3.z));
        a5 += (bfhi(v0.z) + bfhi(v1.z)) + (bfhi(v2.z) + bfhi(v3.z));
        a6 += (bflo(v0.w) + bflo(v1.w)) + (bflo(v2.w) + bflo(v3.w));
        a7 += (bfhi(v0.w) + bfhi(v1.w)) + (bfhi(v2.w) + bfhi(v3.w));
    }
    for (; e < end; e++) {
        int s0 = ell[e];
        uint4 v0 = *(const uint4*)&XbS[(size_t)s0*256 + 128 + lane*8];
        a0 += bflo(v0.x); a1 += bfhi(v0.x);
        a2 += bflo(v0.y); a3 += bfhi(v0.y);
        a4 += bflo(v0.z); a5 += bfhi(v0.z);
        a6 += bflo(v0.w); a7 += bfhi(v0.w);
    }
    float inv = 1.0f / (float)max(dg, 1);
    uint4 o;
    o.x = ((unsigned)bfu(a1*inv) << 16) | (unsigned)bfu(a0*inv);
    o.y = ((unsigned)bfu(a3*inv) << 16) | (unsigned)bfu(a2*inv);
    o.z = ((unsigned)bfu(a5*inv) << 16) | (unsigned)bfu(a4*inv);
    o.w = ((unsigned)bfu(a7*inv) << 16) | (unsigned)bfu(a6*inv);
    *(uint4*)&Xb[(size_t)n*256 + lane*8] = o;
}

// ---------------- FUSED conv2 + MLP + softmax (proven R4 structure) -------
__global__ __launch_bounds__(512, 1) void conv2mlp_k(const __hip_bfloat16* __restrict__ Xb,
        const __hip_bfloat16* __restrict__ Wpk2, const float* __restrict__ bl2,
        const __hip_bfloat16* __restrict__ Wpk1, const float* __restrict__ b1,
        const __hip_bfloat16* __restrict__ W2pk, const float* __restrict__ b2,
        float* __restrict__ out) {
    __shared__ short Ws2[32768];         // conv2 weights [ks8][nt8][lane64][j8]
    __shared__ short Ws1[32768];         // W1 weights [ks4][nt16][lane64][j8]
    __shared__ short Cs[8 * 16 * 128];   // per-wave 16x128 swizzled staging
    int tid = threadIdx.x;
    int lane = tid & 63, wave = tid >> 6;
    int quad = lane >> 4, m = lane & 15, c0 = lane & 15;
    {
        const float4* s2 = (const float4*)Wpk2;
        const float4* s1 = (const float4*)Wpk1;
        float4* d2 = (float4*)Ws2;
        float4* d1 = (float4*)Ws1;
        #pragma unroll
        for (int i = 0; i < 8; i++) {
            d2[tid + i*512] = s2[tid + i*512];
            d1[tid + i*512] = s1[tid + i*512];
        }
    }
    short8 w2f[8];
    #pragma unroll
    for (int ks = 0; ks < 8; ks++)
        w2f[ks] = *(const short8*)&W2pk[(ks*64 + lane)*8];
    float bl2r[8], b1r[16];
    #pragma unroll
    for (int nt = 0; nt < 8; nt++) bl2r[nt] = bl2[nt*16 + c0];
    #pragma unroll
    for (int nt = 0; nt < 16; nt++) b1r[nt] = b1[nt*16 + c0];
    float b2v = (c0 < CDIM) ? b2[c0] : 0.f;
    __syncthreads();
    short* Tw = &Cs[wave * (16 * 128)];

    int tile = blockIdx.x;
    short8 areg[8];
    {
        int row = tile*128 + wave*16 + m;
        int rowL = row < N_NODES ? row : N_NODES - 1;
        const short* Arow = (const short*)Xb + (size_t)rowL * 256;
        #pragma unroll
        for (int ks = 0; ks < 8; ks++)
            areg[ks] = *(const short8*)(Arow + ks*32 + quad*8);
    }
    for (; tile < NT128; tile += gridDim.x) {
        short8 anext[8];
        {
            int tnext = tile + gridDim.x;
            int rown = (tnext < NT128) ? (tnext*128 + wave*16 + m) : 0;
            int rowNL = rown < N_NODES ? rown : N_NODES - 1;
            const short* ArowN = (const short*)Xb + (size_t)rowNL * 256;
            #pragma unroll
            for (int ks = 0; ks < 8; ks++)
                anext[ks] = *(const short8*)(ArowN + ks*32 + quad*8);
        }
        // ---- conv2: h2 = tanh([agg2|h1] @ W' + bl2)
        floatx4 acc2[8];
        #pragma unroll
        for (int i = 0; i < 8; i++)
            #pragma unroll
            for (int r = 0; r < 4; r++) acc2[i][r] = 0.f;
        #pragma unroll
        for (int ks = 0; ks < 8; ks++) {
            #pragma unroll
            for (int nt = 0; nt < 8; nt++) {
                short8 b = *(const short8*)&Ws2[((ks*8 + nt)*64 + lane)*8];
                acc2[nt] = __builtin_amdgcn_mfma_f32_16x16x32_bf16(areg[ks], b, acc2[nt], 0, 0, 0);
            }
        }
        #pragma unroll
        for (int nt = 0; nt < 8; nt++) {
            int cg = nt*2 + (c0 >> 3);
            #pragma unroll
            for (int r = 0; r < 4; r++) {
                int row = quad*4 + r;
                Tw[row*128 + ((cg ^ row) << 3) + (c0 & 7)] =
                    (short)bfu(ftanh(acc2[nt][r] + bl2r[nt]));
            }
        }
        // ---- GEMM1: t_pre = h2 @ W1^T  (A from the slice just written)
        floatx4 acc1[16];
        #pragma unroll
        for (int i = 0; i < 16; i++)
            #pragma unroll
            for (int r = 0; r < 4; r++) acc1[i][r] = 0.f;
        #pragma unroll
        for (int ks = 0; ks < 4; ks++) {
            short8 a = *(const short8*)&Tw[m*128 + (((ks*4 + quad) ^ m) << 3)];
            #pragma unroll
            for (int nt = 0; nt < 16; nt++) {
                short8 b = *(const short8*)&Ws1[((ks*16 + nt)*64 + lane)*8];
                acc1[nt] = __builtin_amdgcn_mfma_f32_16x16x32_bf16(a, b, acc1[nt], 0, 0, 0);
            }
        }
        // ---- GEMM2 in 4 K-chunks through the (now dead) slice
        floatx4 lacc;
        #pragma unroll
        for (int r = 0; r < 4; r++) lacc[r] = 0.f;
        #pragma unroll
        for (int ch = 0; ch < 4; ch++) {
            #pragma unroll
            for (int ntl = 0; ntl < 4; ntl++) {
                int nt = ch*4 + ntl;
                int cg = ntl*2 + (c0 >> 3);
                #pragma unroll
                for (int r = 0; r < 4; r++) {
                    int row = quad*4 + r;
                    Tw[row*128 + ((cg ^ row) << 3) + (c0 & 7)] =
                        (short)bfu(ftanh(acc1[nt][r] + b1r[nt]));
                }
            }
            #pragma unroll
            for (int k2 = 0; k2 < 2; k2++) {
                short8 a = *(const short8*)&Tw[m*128 + (((k2*4 + quad) ^ m) << 3)];
                lacc = __builtin_amdgcn_mfma_f32_16x16x32_bf16(a, w2f[ch*2 + k2], lacc, 0, 0, 0);
            }
        }
        // ---- softmax across the 8 class lanes
        int rbase = tile*128 + wave*16 + quad*4;
        #pragma unroll
        for (int r = 0; r < 4; r++) {
            float v = lacc[r] + b2v;
            float mval = (c0 < CDIM) ? v : -INFINITY;
            #pragma unroll
            for (int off = 1; off < 8; off <<= 1)
                mval = fmaxf(mval, __shfl_xor(mval, off));
            float e = (c0 < CDIM) ? __expf(v - mval) : 0.f;
            float ssum = e;
            #pragma unroll
            for (int off = 1; off < 8; off <<= 1)
                ssum += __shfl_xor(ssum, off);
            int rowg = rbase + r;
            if (c0 < CDIM && rowg < N_NODES)
                out[(size_t)rowg*CDIM + c0] = e / ssum;
        }
        #pragma unroll
        for (int ks = 0; ks < 8; ks++) areg[ks] = anext[ks];
    }
}

extern "C" void kernel_launch(void* const* d_in, const int* in_sizes, int n_in,
                              void* d_out, int out_size, void* d_ws, size_t ws_size,
                              hipStream_t stream) {
    const float* x   = (const float*)d_in[0];
    const int*   ei  = (const int*)d_in[1];
    const float* Wl1 = (const float*)d_in[2];
    const float* bl1 = (const float*)d_in[3];
    const float* Wr1 = (const float*)d_in[4];
    const float* Wl2 = (const float*)d_in[5];
    const float* bl2 = (const float*)d_in[6];
    const float* Wr2 = (const float*)d_in[7];
    const float* W1  = (const float*)d_in[8];
    const float* b1  = (const float*)d_in[9];
    const float* W2  = (const float*)d_in[10];
    const float* b2  = (const float*)d_in[11];

    float* ws     = (float*)d_ws;
    float* part   = ws + OFF_PART;
    int*   deg    = (int*)(ws + OFF_DEG);
    float4* h0    = (float4*)(ws + OFF_H0);
    int*   ell    = (int*)(ws + OFF_ELL);
    int*   cntT   = (int*)(ws + OFF_CNTT);
    int2*  scratch= (int2*)(ws + OFF_SCR);
    __hip_bfloat16* Wpk2 = (__hip_bfloat16*)(ws + OFF_WPK2);
    __hip_bfloat16* Wpk1 = (__hip_bfloat16*)(ws + OFF_WPK1);
    __hip_bfloat16* W2pk = (__hip_bfloat16*)(ws + OFF_W2PK);
    __hip_bfloat16* Xb   = (__hip_bfloat16*)(ws + OFF_XB);

    statsPart_k<<<NB_STATS + NBLK_P1, 256, 0, stream>>>(x, part, ei, cntT, scratch);
    binNorm_k<<<NBUCK + NB_NODE, 256, 0, stream>>>(x, part, h0,
            Wl2, Wr2, W1, W2, Wpk2, Wpk1, W2pk, cntT, scratch, ell, deg);
    agg1conv1_k<<<NB_NODE, 256, 0, stream>>>(h0, deg, ell,
            Wl1, bl1, Wr1, Xb);
    agg2_k<<<N_NODES / 16, 256, 0, stream>>>(Xb, deg, ell);
    conv2mlp_k<<<256, 512, 0, stream>>>(Xb, Wpk2, bl2, Wpk1, b1, W2pk, b2,
            (float*)d_out);
}